// Round 8
// baseline (2016.549 us; speedup 1.0000x reference)
//
#include <hip/hip_runtime.h>
#include <hip/hip_fp16.h>

#define N_NODES 50000
#define N_EDGES 800000
#define NPAD    50176          // 392*128: graph-2 node base, bucket-aligned
#define BNODES  128            // nodes per bucket
#define NBKT    784            // (2*NPAD)/128 buckets
#define G2BKT   392            // first graph-2 bucket
#define BCAP    3072           // bucket capacity; mean 2048, sigma 45 -> +22 sigma
#define ASTRIDE 65             // LDS acc row stride (floats): bank = (d+feat)%32
static_assert(N_NODES < 65536, "u16 src ids");
// LAYOUT RULE: all intermediate buffers indexed by PADDED gid (g*NPAD + i).
// Compaction to the harness's [2*N_NODES,64] output only at pull-2's store.
// Gather-side feature buffers (sxh, bufH, gh) are fp16; accumulation fp32.

// Per-block edge-index stride detection (int64 vs int32): odd 32-bit words of
// little-endian int64 with values < 2^31 are all zero.
__device__ __forceinline__ int detect_stride_block(const int* raw1, int* sflag) {
    int odd = 0;
    for (int i = threadIdx.x; i < 2048; i += 256) odd |= raw1[2 * i + 1];
    if (threadIdx.x == 0) *sflag = 0;
    __syncthreads();
    if (odd) atomicOr(sflag, 1);
    __syncthreads();
    return *sflag ? 1 : 2;
}

// ---------------------------------------------------------------------------
// Single-pass edge binning: pos = atomicAdd(bucket cursor), write
// (dst_in_bucket << 16) | src. 784 cursors -> light contention; bucket
// frontier lines stay L2-resident -> ~no write amplification.
// ---------------------------------------------------------------------------
__global__ __launch_bounds__(256) void binA_k(const int* __restrict__ raw1,
        const int* __restrict__ raw2, unsigned* __restrict__ bcount,
        unsigned* __restrict__ bbuf) {
    __shared__ int sflag;
    const int stride = detect_stride_block(raw1, &sflag);
    const long long step = (long long)gridDim.x * 256;
    for (long long e = (long long)blockIdx.x * 256 + threadIdx.x;
         e < 2LL * N_EDGES; e += step) {
        int g2 = e >= N_EDGES;
        const int* raw = g2 ? raw2 : raw1;
        long long el = e - (g2 ? N_EDGES : 0);
        int s = raw[el * stride];
        int d = raw[((long long)N_EDGES + el) * stride];
        int bkt = (g2 ? NPAD + d : d) >> 7;
        unsigned pos = atomicAdd(&bcount[bkt], 1u);
        if (pos < BCAP)
            bbuf[(size_t)bkt * BCAP + pos] =
                ((unsigned)(d & (BNODES - 1)) << 16) | (unsigned)s;
    }
}

// ---------------------------------------------------------------------------
// prep: per bucket, degree histogram -> dinv; fp16 prescale sxh = dinv * x.
// Pad nodes (local >= N_NODES): deg 0, dinv 1, sxh 0.
// ---------------------------------------------------------------------------
__global__ __launch_bounds__(256) void prep_k(const unsigned* __restrict__ bcount,
        const unsigned* __restrict__ bbuf, const float* __restrict__ x1,
        const float* __restrict__ x2, float* __restrict__ dinv,
        __half* __restrict__ sxh) {
    __shared__ int deg[BNODES];
    __shared__ float sdinv[BNODES];
    const int b = blockIdx.x, tid = threadIdx.x;
    if (tid < BNODES) deg[tid] = 0;
    __syncthreads();
    const int cnt = min((int)bcount[b], BCAP);
    const unsigned* eb = bbuf + (size_t)b * BCAP;
    for (int i = tid; i < cnt; i += 256) atomicAdd(&deg[eb[i] >> 16], 1);
    __syncthreads();
    if (tid < BNODES) {
        float dv = rsqrtf((float)deg[tid] + 1.0f);   // +1 self-loop
        dinv[b * BNODES + tid] = dv;
        sdinv[tid] = dv;
    }
    __syncthreads();
    const int g2 = b >= G2BKT;
    const float* x = g2 ? x2 : x1;
    const int lbase = b * BNODES - (g2 ? NPAD : 0);
    for (int i = tid; i < BNODES * 16; i += 256) {    // (node, float4-chunk)
        int n = i >> 4, q = i & 15;
        int local = lbase + n;
        __half2 lo = __floats2half2_rn(0.f, 0.f), hi = lo;
        if (local < N_NODES) {
            float4 vx = *(const float4*)&x[((size_t)local * 16 + q) * 4];
            float dn = sdinv[n];
            lo = __floats2half2_rn(vx.x * dn, vx.y * dn);
            hi = __floats2half2_rn(vx.z * dn, vx.w * dn);
        }
        uint2 u; u.x = *(unsigned*)&lo; u.y = *(unsigned*)&hi;
        *(uint2*)&sxh[(size_t)(b * BNODES + n) * 64 + q * 4] = u;
    }
}

// ---------------------------------------------------------------------------
// Edge-centric pull: one 512-thread block per bucket; fp32 LDS accumulators
// acc[128][65] (33.3 KB -> 4 blocks/CU, 32 waves). Each wave: 8 edges/iter
// (8 subs x 8 lanes x 8 halfs), unroll 2. Unordered dsts -> LDS ds_add_f32
// conflicts ~2-way (free). Epilogue: o = dinv*(acc + self) (+bias,relu).
// ---------------------------------------------------------------------------
template<bool BIAS_RELU, bool COMPACT_OUT>
__global__ __launch_bounds__(512, 8) void pull_agg_k(const __half* __restrict__ sh,
        const unsigned* __restrict__ bcount, const unsigned* __restrict__ bbuf,
        const float* __restrict__ dinv, const float* __restrict__ bias,
        float* __restrict__ out) {
    __shared__ float acc[BNODES * ASTRIDE];
    const int b = blockIdx.x, tid = threadIdx.x;
    for (int i = tid; i < BNODES * ASTRIDE; i += 512) acc[i] = 0.f;
    const int cnt = min((int)bcount[b], BCAP);
    const int g2 = b >= G2BKT;
    const int gbase = g2 ? NPAD : 0;
    const unsigned* eb = bbuf + (size_t)b * BCAP;
    const int lane = tid & 63, w = tid >> 6;         // 8 waves
    const int sub = lane >> 3, fl = lane & 7;        // 8 edges x 8 feature-lanes
    __syncthreads();
    int j = w * 8 + sub;
    #define ACC8(aptr, u) { float2 f_;                                          \
        f_ = __half22float2(*(__half2*)&(u).x); atomicAdd((aptr)+0, f_.x); atomicAdd((aptr)+1, f_.y); \
        f_ = __half22float2(*(__half2*)&(u).y); atomicAdd((aptr)+2, f_.x); atomicAdd((aptr)+3, f_.y); \
        f_ = __half22float2(*(__half2*)&(u).z); atomicAdd((aptr)+4, f_.x); atomicAdd((aptr)+5, f_.y); \
        f_ = __half22float2(*(__half2*)&(u).w); atomicAdd((aptr)+6, f_.x); atomicAdd((aptr)+7, f_.y); }
    for (; j + 64 < cnt; j += 128) {
        unsigned p0 = eb[j], p1 = eb[j + 64];
        int s0 = (int)(p0 & 0xFFFFu) + gbase, d0 = (int)(p0 >> 16);
        int s1 = (int)(p1 & 0xFFFFu) + gbase, d1 = (int)(p1 >> 16);
        uint4 u0 = *(const uint4*)&sh[(size_t)s0 * 64 + fl * 8];
        uint4 u1 = *(const uint4*)&sh[(size_t)s1 * 64 + fl * 8];
        float* a0 = &acc[d0 * ASTRIDE + fl * 8];
        float* a1 = &acc[d1 * ASTRIDE + fl * 8];
        ACC8(a0, u0);
        ACC8(a1, u1);
    }
    for (; j < cnt; j += 64) {
        unsigned p = eb[j];
        int s = (int)(p & 0xFFFFu) + gbase, d = (int)(p >> 16);
        uint4 u = *(const uint4*)&sh[(size_t)s * 64 + fl * 8];
        float* a = &acc[d * ASTRIDE + fl * 8];
        ACC8(a, u);
    }
    #undef ACC8
    __syncthreads();
    // epilogue: 4 rounds x (32 nodes x 16 chunks); scalar LDS reads are
    // conflict-free: bank = (n + 4q + k) % 32 covers all banks 2-way.
    for (int r = 0; r < 4; r++) {
        int n = r * 32 + (tid >> 4), q = tid & 15;
        int gid = b * BNODES + n;
        int local = gid - gbase;
        const float* a = &acc[n * ASTRIDE + q * 4];
        uint2 su = *(const uint2*)&sh[(size_t)gid * 64 + q * 4];
        float2 sf0 = __half22float2(*(__half2*)&su.x);
        float2 sf1 = __half22float2(*(__half2*)&su.y);
        float dv = dinv[gid];
        float4 o;
        o.x = (a[0] + sf0.x) * dv;
        o.y = (a[1] + sf0.y) * dv;
        o.z = (a[2] + sf1.x) * dv;
        o.w = (a[3] + sf1.y) * dv;
        if (BIAS_RELU) {
            float4 bv = *(const float4*)&bias[q * 4];
            o.x = fmaxf(o.x + bv.x, 0.f);
            o.y = fmaxf(o.y + bv.y, 0.f);
            o.z = fmaxf(o.z + bv.z, 0.f);
            o.w = fmaxf(o.w + bv.w, 0.f);
        }
        if (!COMPACT_OUT) {
            *(float4*)&out[(size_t)gid * 64 + q * 4] = o;   // padded (pads = 0)
        } else if (local < N_NODES) {
            size_t orow = (size_t)(g2 ? N_NODES + local : local);
            *(float4*)&out[orow * 64 + q * 4] = o;
        }
    }
}

// ---------------------------------------------------------------------------
// H = X @ W, fused epilogue, PADDED rows, fp16 output. Per-thread 8 rows x
// 4 cols; X via XOR-swizzled LDS. IN_HALF: stage fp16 input (cvt to fp32).
// EPI 0: relu(acc + b).  EPI 1: acc * dinv[row] (prescale for next pull).
// ---------------------------------------------------------------------------
template<int K, int M, int CG, int RPT, int KH, bool IN_HALF, int EPI>
__global__ __launch_bounds__(256) void gemm_xw_k(const void* __restrict__ Xv,
        const float* __restrict__ W, const float* __restrict__ b,
        const float* __restrict__ dinv, __half* __restrict__ Hh, int nrows) {
    constexpr int RT  = 256 / CG;
    constexpr int RPB = RT * RPT;
    constexpr int KHS = K / KH;
    constexpr int Q   = KHS / 4;
    __shared__ float Wl[K * M];
    __shared__ float Xl[RPB * KHS];
    const int tid = threadIdx.x;
    const int cg = tid % CG, rt = tid / CG;
    const int row0 = blockIdx.x * RPB;
    for (int i = tid * 4; i < K * M; i += 1024)
        *(float4*)&Wl[i] = *(const float4*)&W[i];
    float4 acc[RPT] = {};
    for (int h = 0; h < KH; h++) {
        __syncthreads();
        for (int i4 = tid; i4 < RPB * Q; i4 += 256) {
            int rr = i4 / Q, q = i4 % Q;
            int grow = row0 + rr;
            float4 v = {0.f, 0.f, 0.f, 0.f};
            if (grow < nrows) {
                if (!IN_HALF) {
                    v = *(const float4*)&((const float*)Xv)[(size_t)grow * K + h * KHS + q * 4];
                } else {
                    uint2 u = *(const uint2*)&((const __half*)Xv)[(size_t)grow * K + h * KHS + q * 4];
                    float2 f0 = __half22float2(*(__half2*)&u.x);
                    float2 f1 = __half22float2(*(__half2*)&u.y);
                    v = make_float4(f0.x, f0.y, f1.x, f1.y);
                }
            }
            ((float4*)Xl)[rr * Q + (q ^ (rr & (Q - 1)))] = v;
        }
        __syncthreads();
        for (int k4 = 0; k4 < Q; k4++) {
            float xr[RPT][4];
            #pragma unroll
            for (int i = 0; i < RPT; i++) {
                int rr = rt * RPT + i;
                float4 xv = ((const float4*)Xl)[rr * Q + (k4 ^ (rr & (Q - 1)))];
                xr[i][0] = xv.x; xr[i][1] = xv.y; xr[i][2] = xv.z; xr[i][3] = xv.w;
            }
            #pragma unroll
            for (int kk = 0; kk < 4; kk++) {
                int k = h * KHS + k4 * 4 + kk;
                float4 w4 = *(const float4*)&Wl[k * M + cg * 4];
                #pragma unroll
                for (int i = 0; i < RPT; i++) {
                    acc[i].x = fmaf(xr[i][kk], w4.x, acc[i].x);
                    acc[i].y = fmaf(xr[i][kk], w4.y, acc[i].y);
                    acc[i].z = fmaf(xr[i][kk], w4.z, acc[i].z);
                    acc[i].w = fmaf(xr[i][kk], w4.w, acc[i].w);
                }
            }
        }
    }
    float4 bv = {0.f, 0.f, 0.f, 0.f};
    if (EPI == 0) bv = *(const float4*)&b[cg * 4];
    #pragma unroll
    for (int i = 0; i < RPT; i++) {
        int grow = row0 + rt * RPT + i;
        if (grow < nrows) {
            float4 o = acc[i];
            if (EPI == 0) {
                o.x = fmaxf(o.x + bv.x, 0.f);
                o.y = fmaxf(o.y + bv.y, 0.f);
                o.z = fmaxf(o.z + bv.z, 0.f);
                o.w = fmaxf(o.w + bv.w, 0.f);
            } else {
                float dv = dinv[grow];
                o.x *= dv; o.y *= dv; o.z *= dv; o.w *= dv;
            }
            __half2 lo = __floats2half2_rn(o.x, o.y);
            __half2 hi = __floats2half2_rn(o.z, o.w);
            uint2 u; u.x = *(unsigned*)&lo; u.y = *(unsigned*)&hi;
            *(uint2*)&Hh[(size_t)grow * M + cg * 4] = u;
        }
    }
}

extern "C" void kernel_launch(void* const* d_in, const int* in_sizes, int n_in,
                              void* d_out, int out_size, void* d_ws, size_t ws_size,
                              hipStream_t stream) {
    const float* x1 = (const float*)d_in[0];
    const int*   e1 = (const int*)d_in[1];
    const float* x2 = (const float*)d_in[2];
    const int*   e2 = (const int*)d_in[3];
    const float* W1 = (const float*)d_in[4];
    const float* b1 = (const float*)d_in[5];
    const float* W2 = (const float*)d_in[6];
    const float* b2 = (const float*)d_in[7];
    float* out = (float*)d_out;

    // Workspace (~75 MB), 256 B-aligned chunks.
    char* p = (char*)d_ws;
    auto alloc = [&](size_t bytes) { char* r = p; p += (bytes + 255) & ~(size_t)255; return r; };
    unsigned* bcount = (unsigned*)alloc(NBKT * 4);
    float*    dinv   = (float*)alloc((size_t)2 * NPAD * 4);
    unsigned* bbuf   = (unsigned*)alloc((size_t)NBKT * BCAP * 4);
    __half*   sxh    = (__half*)alloc((size_t)2 * NPAD * 64 * 2);   // fp16 feats
    float*    bufY   = (float*)alloc((size_t)2 * NPAD * 64 * 4);    // fp32 (gemm1 in)
    __half*   bufH   = (__half*)alloc((size_t)2 * NPAD * 128 * 2);  // fp16 X1
    __half*   gh     = sxh;    // alias: sxh dead after pull-1; gemm2 writes gh

    // ---- bucket build: bin + (deg,dinv,prescale) ----
    hipMemsetAsync(bcount, 0, NBKT * 4, stream);
    binA_k<<<784, 256, 0, stream>>>(e1, e2, bcount, bbuf);
    prep_k<<<NBKT, 256, 0, stream>>>(bcount, bbuf, x1, x2, dinv, sxh);

    // ---- layer 1: Y = A_hat @ X (fp16 feats), X1 = fp16(relu(Y@W1 + b1)) ----
    pull_agg_k<false, false><<<NBKT, 512, 0, stream>>>(sxh, bcount, bbuf, dinv, nullptr, bufY);
    gemm_xw_k<64, 128, 32, 8, 1, false, 0><<<2 * NPAD / 64, 256, 0, stream>>>(bufY, W1, b1, nullptr, bufH, 2 * NPAD);
    // ---- layer 2: G' = fp16(dinv*(X1@W2)), out = relu(dinv*(sum+self)+b2) ----
    gemm_xw_k<128, 64, 16, 8, 2, true, 1><<<2 * NPAD / 128, 256, 0, stream>>>(bufH, W2, nullptr, dinv, gh, 2 * NPAD);
    pull_agg_k<true, true><<<NBKT, 512, 0, stream>>>(gh, bcount, bbuf, dinv, b2, out);
}

// Round 9
// 278.278 us; speedup vs baseline: 7.2465x; 7.2465x over previous
//
#include <hip/hip_runtime.h>
#include <hip/hip_fp16.h>

#define N_NODES 50000
#define N_EDGES 800000
#define NPAD    50176          // 196*256: graph-2 node base, bucket-aligned
#define NBKT    392            // (2*NPAD)/256 buckets of 256 nodes
#define BCAP    6144           // bucket capacity; mean 4082, sigma 64 -> +32 sigma
static_assert(N_NODES < 65536, "u16 CSR requires local node ids < 65536");
// LAYOUT RULE: all intermediate buffers indexed by PADDED gid (g*NPAD + i).
// Compaction to the harness's [2*N_NODES,64] output only at pull-2's store.
// Gather/GEMM feature buffers are fp16; all accumulation fp32 (MFMA C=f32).

typedef _Float16 __attribute__((ext_vector_type(8))) half8;
typedef float    __attribute__((ext_vector_type(4))) floatx4;

// Per-block edge-index stride detection (int64 vs int32): odd 32-bit words of
// little-endian int64 with values < 2^31 are all zero.
__device__ __forceinline__ int detect_stride_block(const int* raw1, int* sflag) {
    int odd = 0;
    for (int i = threadIdx.x; i < 2048; i += 256) odd |= raw1[2 * i + 1];
    if (threadIdx.x == 0) *sflag = 0;
    __syncthreads();
    if (odd) atomicOr(sflag, 1);
    __syncthreads();
    return *sflag ? 1 : 2;
}

// ---------------------------------------------------------------------------
// Pass A: bin edges by dst bucket (bucket = gid>>8). Per-block LDS histogram
// -> one global atomicAdd per (block,bucket) reserves a contiguous run in
// bbuf. Entry: (dst_in_bucket << 16) | src_local.   [R7-verified]
// ---------------------------------------------------------------------------
__global__ __launch_bounds__(256) void binA_k(const int* __restrict__ raw1,
        const int* __restrict__ raw2, unsigned* __restrict__ bcount,
        unsigned* __restrict__ bbuf) {
    __shared__ unsigned hist[NBKT], gofs[NBKT];
    __shared__ int sflag;
    const int stride = detect_stride_block(raw1, &sflag);
    const int tid = threadIdx.x;
    for (int b = tid; b < NBKT; b += 256) hist[b] = 0u;
    __syncthreads();
    const long long e0 = (long long)blockIdx.x * 8192;
    #pragma unroll 4
    for (int it = 0; it < 32; it++) {
        long long e = e0 + it * 256 + tid;
        if (e < 2LL * N_EDGES) {
            int g2 = e >= N_EDGES;
            const int* raw = g2 ? raw2 : raw1;
            long long el = e - (g2 ? N_EDGES : 0);
            int d = raw[((long long)N_EDGES + el) * stride];
            atomicAdd(&hist[(g2 * NPAD + d) >> 8], 1u);
        }
    }
    __syncthreads();
    for (int b = tid; b < NBKT; b += 256) {
        unsigned c = hist[b];
        gofs[b] = c ? atomicAdd(&bcount[b], c) : 0u;
    }
    __syncthreads();
    for (int b = tid; b < NBKT; b += 256) hist[b] = 0u;
    __syncthreads();
    #pragma unroll 4
    for (int it = 0; it < 32; it++) {
        long long e = e0 + it * 256 + tid;
        if (e < 2LL * N_EDGES) {
            int g2 = e >= N_EDGES;
            const int* raw = g2 ? raw2 : raw1;
            long long el = e - (g2 ? N_EDGES : 0);
            int s = raw[el * stride];
            int d = raw[((long long)N_EDGES + el) * stride];
            int gid = g2 * NPAD + d;
            int bkt = gid >> 8;
            unsigned r = atomicAdd(&hist[bkt], 1u);
            unsigned pos = gofs[bkt] + r;
            if (pos < BCAP)
                bbuf[(size_t)bkt * BCAP + pos] =
                    ((unsigned)(gid & 255) << 16) | (unsigned)s;
        }
    }
}

// ---------------------------------------------------------------------------
// Pass B: one block per bucket. Bucket-count scan -> CSR base; per-node
// degree + rowptr + dinv; LDS-cursor CSR scatter; fused fp16 prescale
// sxh = dinv * x for this bucket's 256 nodes.   [R7-verified]
// ---------------------------------------------------------------------------
__global__ __launch_bounds__(256) void buildB_k(const unsigned* __restrict__ bcount,
        const unsigned* __restrict__ bbuf, const float* __restrict__ x1,
        const float* __restrict__ x2, unsigned short* __restrict__ csr,
        int* __restrict__ rowptr, float* __restrict__ dinv,
        __half* __restrict__ sxh) {
    __shared__ unsigned ent[BCAP];
    __shared__ int deg[256], cur[256], tmp[256], tmp2[512];
    __shared__ float sdinv[256];
    const int b = blockIdx.x, tid = threadIdx.x;
    {
        int v = (tid < NBKT) ? (int)bcount[tid] : 0;
        tmp2[tid] = v; tmp2[tid + 256] = (tid + 256 < NBKT) ? (int)bcount[tid + 256] : 0;
        __syncthreads();
        #pragma unroll
        for (int off = 1; off < 512; off <<= 1) {
            int a0 = (tid >= off) ? tmp2[tid - off] : 0;
            int a1 = (tid + 256 >= off) ? tmp2[tid + 256 - off] : 0;
            __syncthreads();
            tmp2[tid] += a0; tmp2[tid + 256] += a1;
            __syncthreads();
        }
    }
    const int cnt = min((int)bcount[b], BCAP);
    const int eb = tmp2[b] - (int)bcount[b];
    for (int i = tid; i < cnt; i += 256) ent[i] = bbuf[(size_t)b * BCAP + i];
    deg[tid] = 0;
    __syncthreads();
    for (int i = tid; i < cnt; i += 256) atomicAdd(&deg[ent[i] >> 16], 1);
    __syncthreads();
    int v = deg[tid];
    tmp[tid] = v;
    __syncthreads();
    #pragma unroll
    for (int off = 1; off < 256; off <<= 1) {
        int add = (tid >= off) ? tmp[tid - off] : 0;
        __syncthreads();
        tmp[tid] += add;
        __syncthreads();
    }
    int excl = tmp[tid] - v;
    cur[tid] = excl;
    const int gid = b * 256 + tid;
    float dv = rsqrtf((float)v + 1.0f);          // +1 self-loop
    rowptr[gid] = eb + excl;
    dinv[gid] = dv;
    sdinv[tid] = dv;
    if (b == NBKT - 1 && tid == 255) rowptr[2 * NPAD] = eb + excl + v;
    __syncthreads();
    for (int i = tid; i < cnt; i += 256) {
        unsigned p = ent[i];
        int pos = atomicAdd(&cur[p >> 16], 1);
        csr[eb + pos] = (unsigned short)(p & 0xFFFFu);
    }
    const int g2 = (b * 256) >= NPAD;
    const float* x = g2 ? x2 : x1;
    const int lbase = b * 256 - (g2 ? NPAD : 0);
    for (int i = tid; i < 256 * 16; i += 256) {
        int n = i >> 4, q = i & 15;
        int local = lbase + n;
        __half2 lo = __floats2half2_rn(0.f, 0.f), hi = lo;
        if (local < N_NODES) {
            float4 vx = *(const float4*)&x[((size_t)local * 16 + q) * 4];
            float dn = sdinv[n];
            lo = __floats2half2_rn(vx.x * dn, vx.y * dn);
            hi = __floats2half2_rn(vx.z * dn, vx.w * dn);
        }
        uint2 u; u.x = *(unsigned*)&lo; u.y = *(unsigned*)&hi;
        *(uint2*)&sxh[(size_t)(b * 256 + n) * 64 + q * 4] = u;
    }
}

// ---------------------------------------------------------------------------
// Pack W into MFMA B-fragment order (fp16):
// Wf[(kc*NT+nt)*512 + lane*8 + j] = W[kc*32 + (lane>>4)*8 + j][nt*16 + (lane&15)]
// so a wave loads one frag as a coalesced half8 per lane. Block 0: W1; 1: W2.
// ---------------------------------------------------------------------------
__global__ __launch_bounds__(256) void wprep_k(const float* __restrict__ W1,
        const float* __restrict__ W2, _Float16* __restrict__ Wf1,
        _Float16* __restrict__ Wf2) {
    const float* W = blockIdx.x ? W2 : W1;
    _Float16* Wf = blockIdx.x ? Wf2 : Wf1;
    const int M = blockIdx.x ? 64 : 128;
    const int NT = M / 16;
    for (int i = threadIdx.x; i < 8192; i += 256) {   // 16 frags x 512
        int f = i >> 9, r = i & 511;
        int lane = r >> 3, j = r & 7;
        int kc = f / NT, nt = f % NT;
        int k = kc * 32 + (lane >> 4) * 8 + j;
        int m = nt * 16 + (lane & 15);
        Wf[i] = (_Float16)W[k * M + m];
    }
}

// ---------------------------------------------------------------------------
// Pull aggregation on PRESCALED fp16 features: one wave per dst node.
// Lane = (sub, fl): 4 edges in parallel, 16 lanes x 4 halfs (uint2) per edge.
// Gather pairs are pre-summed in fp16 (v_pk_add_f16) then flushed to fp32:
// one extra fp16 rounding per edge-pair (~storage-rounding magnitude).
// OUT_HALF: padded fp16 out (feeds MFMA gemm). else fp32 (compact if set).
// ---------------------------------------------------------------------------
template<bool BIAS_RELU, bool COMPACT_OUT, bool OUT_HALF>
__global__ __launch_bounds__(256) void pull_agg_k(const __half* __restrict__ sh,
        const unsigned short* __restrict__ csr, const int* __restrict__ rowptr,
        const float* __restrict__ dinv, const float* __restrict__ bias,
        void* __restrict__ outv) {
    const int lane = threadIdx.x & 63;
    const int d = blockIdx.x * 4 + (threadIdx.x >> 6);   // grid exact: d < 2*NPAD
    const int g2 = d >= NPAD;
    const int local = d - (g2 ? NPAD : 0);
    if (local >= N_NODES) return;                         // pad node: never gathered
    const int sub = lane >> 4, fl = lane & 15;
    const int gbase = g2 ? NPAD : 0;
    const int jb = rowptr[d], je = rowptr[d + 1];
    float4 acc = {0.f, 0.f, 0.f, 0.f};
    int j = jb;
    for (; j + 16 <= je; j += 16) {
        int s0 = (int)csr[j      + sub] + gbase;
        int s1 = (int)csr[j + 4  + sub] + gbase;
        int s2 = (int)csr[j + 8  + sub] + gbase;
        int s3 = (int)csr[j + 12 + sub] + gbase;
        uint2 u0 = *(const uint2*)&sh[(size_t)s0 * 64 + fl * 4];
        uint2 u1 = *(const uint2*)&sh[(size_t)s1 * 64 + fl * 4];
        uint2 u2 = *(const uint2*)&sh[(size_t)s2 * 64 + fl * 4];
        uint2 u3 = *(const uint2*)&sh[(size_t)s3 * 64 + fl * 4];
        __half2 pa = __hadd2(*(__half2*)&u0.x, *(__half2*)&u1.x);
        __half2 pb = __hadd2(*(__half2*)&u0.y, *(__half2*)&u1.y);
        __half2 pc = __hadd2(*(__half2*)&u2.x, *(__half2*)&u3.x);
        __half2 pd = __hadd2(*(__half2*)&u2.y, *(__half2*)&u3.y);
        float2 fa = __half22float2(pa), fb = __half22float2(pb);
        float2 fc = __half22float2(pc), fd = __half22float2(pd);
        acc.x += fa.x + fc.x; acc.y += fa.y + fc.y;
        acc.z += fb.x + fd.x; acc.w += fb.y + fd.y;
    }
    for (; j < je; j += 4) {
        int idx = j + sub;
        int ii = (idx < je) ? idx : jb;              // safe addr (row nonempty here)
        int s = (int)csr[ii] + gbase;
        uint2 u = *(const uint2*)&sh[(size_t)s * 64 + fl * 4];
        if (idx < je) {
            float2 f0 = __half22float2(*(__half2*)&u.x);
            float2 f1 = __half22float2(*(__half2*)&u.y);
            acc.x += f0.x; acc.y += f0.y; acc.z += f1.x; acc.w += f1.y;
        }
    }
    acc.x += __shfl_xor(acc.x, 16); acc.y += __shfl_xor(acc.y, 16);
    acc.z += __shfl_xor(acc.z, 16); acc.w += __shfl_xor(acc.w, 16);
    acc.x += __shfl_xor(acc.x, 32); acc.y += __shfl_xor(acc.y, 32);
    acc.z += __shfl_xor(acc.z, 32); acc.w += __shfl_xor(acc.w, 32);
    uint2 su = *(const uint2*)&sh[(size_t)d * 64 + fl * 4];
    float2 sf0 = __half22float2(*(__half2*)&su.x);
    float2 sf1 = __half22float2(*(__half2*)&su.y);
    float dv = dinv[d];
    float4 o;
    o.x = (acc.x + sf0.x) * dv;
    o.y = (acc.y + sf0.y) * dv;
    o.z = (acc.z + sf1.x) * dv;
    o.w = (acc.w + sf1.y) * dv;
    if (BIAS_RELU) {
        float4 bv = *(const float4*)&bias[fl * 4];
        o.x = fmaxf(o.x + bv.x, 0.f);
        o.y = fmaxf(o.y + bv.y, 0.f);
        o.z = fmaxf(o.z + bv.z, 0.f);
        o.w = fmaxf(o.w + bv.w, 0.f);
    }
    if (sub == 0) {
        if (OUT_HALF) {
            __half2 lo = __floats2half2_rn(o.x, o.y);
            __half2 hi = __floats2half2_rn(o.z, o.w);
            uint2 u; u.x = *(unsigned*)&lo; u.y = *(unsigned*)&hi;
            *(uint2*)&((__half*)outv)[(size_t)d * 64 + fl * 4] = u;   // padded
        } else {
            size_t orow = COMPACT_OUT ? (size_t)(g2 ? N_NODES + local : local)
                                      : (size_t)d;
            *(float4*)&((float*)outv)[orow * 64 + fl * 4] = o;
        }
    }
}

// ---------------------------------------------------------------------------
// MFMA GEMM: H(fp16) = epi(X(fp16) @ W). v_mfma_f32_16x16x32_f16.
// A frag: A[m=lane&15][k=(lane>>4)*8+j] -> contiguous half8 per lane from
// row-major X. B frags preloaded from wprep layout (coalesced half8).
// C/D: col=lane&15, row=(lane>>4)*4+reg  [HW-verified mapping].
// Wave: RT=2 row-tiles x all NT col-tiles; block = 4 waves = 128 rows.
// Grid 784 exact (100352 rows, padded) -> no bounds checks.
// EPI 0: relu(v + bias[col]). EPI 1: v * dinv[row] (prescale for pull-2).
// ---------------------------------------------------------------------------
template<int K, int M, int EPI>
__global__ __launch_bounds__(256) void mfma_gemm_k(const _Float16* __restrict__ X,
        const _Float16* __restrict__ Wf, const float* __restrict__ bias,
        const float* __restrict__ dinv, _Float16* __restrict__ H) {
    constexpr int KC = K / 32, NT = M / 16, RT = 2;
    const int tid = threadIdx.x;
    const int wv = tid >> 6, lane = tid & 63;
    const int quad = lane >> 4, c = lane & 15;
    const int row0 = blockIdx.x * (4 * RT * 16) + wv * (RT * 16);
    half8 bf[KC][NT];
    #pragma unroll
    for (int kc = 0; kc < KC; kc++)
        #pragma unroll
        for (int nt = 0; nt < NT; nt++)
            bf[kc][nt] = *(const half8*)&Wf[((kc * NT + nt) * 64 + lane) * 8];
    floatx4 acc[RT][NT] = {};
    #pragma unroll
    for (int rt = 0; rt < RT; rt++) {
        half8 a[KC];
        #pragma unroll
        for (int kc = 0; kc < KC; kc++)
            a[kc] = *(const half8*)&X[(size_t)(row0 + rt * 16 + c) * K + kc * 32 + quad * 8];
        #pragma unroll
        for (int nt = 0; nt < NT; nt++)
            #pragma unroll
            for (int kc = 0; kc < KC; kc++)
                acc[rt][nt] = __builtin_amdgcn_mfma_f32_16x16x32_f16(
                    a[kc], bf[kc][nt], acc[rt][nt], 0, 0, 0);
    }
    float bv[NT];
    if (EPI == 0) {
        #pragma unroll
        for (int nt = 0; nt < NT; nt++) bv[nt] = bias[nt * 16 + c];
    }
    #pragma unroll
    for (int rt = 0; rt < RT; rt++) {
        const int rbase = row0 + rt * 16 + quad * 4;
        float4 dvv = {0.f, 0.f, 0.f, 0.f};
        if (EPI == 1) dvv = *(const float4*)&dinv[rbase];
        #pragma unroll
        for (int nt = 0; nt < NT; nt++)
            #pragma unroll
            for (int reg = 0; reg < 4; reg++) {
                float v = acc[rt][nt][reg];
                if (EPI == 0) v = fmaxf(v + bv[nt], 0.f);
                else          v *= ((const float*)&dvv)[reg];
                H[(size_t)(rbase + reg) * M + nt * 16 + c] = (_Float16)v;
            }
    }
}

extern "C" void kernel_launch(void* const* d_in, const int* in_sizes, int n_in,
                              void* d_out, int out_size, void* d_ws, size_t ws_size,
                              hipStream_t stream) {
    const float* x1 = (const float*)d_in[0];
    const int*   e1 = (const int*)d_in[1];
    const float* x2 = (const float*)d_in[2];
    const int*   e2 = (const int*)d_in[3];
    const float* W1 = (const float*)d_in[4];
    const float* b1 = (const float*)d_in[5];
    const float* W2 = (const float*)d_in[6];
    const float* b2 = (const float*)d_in[7];
    float* out = (float*)d_out;

    // Workspace (~70 MB), 256 B-aligned chunks.
    char* p = (char*)d_ws;
    auto alloc = [&](size_t bytes) { char* r = p; p += (bytes + 255) & ~(size_t)255; return r; };
    unsigned* bcount = (unsigned*)alloc(NBKT * 4);
    float*    dinv   = (float*)alloc((size_t)2 * NPAD * 4);
    int*      rowptr = (int*)alloc(((size_t)2 * NPAD + 1) * 4);
    unsigned* bbuf   = (unsigned*)alloc((size_t)NBKT * BCAP * 4);
    unsigned short* csr = (unsigned short*)alloc((size_t)2 * N_EDGES * 2);
    __half*   sxh    = (__half*)alloc((size_t)2 * NPAD * 64 * 2);    // fp16 feats
    _Float16* bufYh  = (_Float16*)alloc((size_t)2 * NPAD * 64 * 2);  // fp16 Y
    _Float16* bufH   = (_Float16*)alloc((size_t)2 * NPAD * 128 * 2); // fp16 X1
    _Float16* Wf1    = (_Float16*)alloc(8192 * 2);
    _Float16* Wf2    = (_Float16*)alloc(8192 * 2);
    __half*   gh     = sxh;   // alias: sxh dead after pull-1; gemm-2 writes gh

    // ---- CSR build + dinv + fp16 prescale + W fragment pack ----
    hipMemsetAsync(bcount, 0, NBKT * 4, stream);
    binA_k<<<196, 256, 0, stream>>>(e1, e2, bcount, bbuf);
    buildB_k<<<NBKT, 256, 0, stream>>>(bcount, bbuf, x1, x2, csr, rowptr, dinv, sxh);
    wprep_k<<<2, 256, 0, stream>>>(W1, W2, Wf1, Wf2);

    // ---- layer 1: Y = A_hat @ X (fp16), X1 = fp16(relu(Y@W1 + b1)) ----
    pull_agg_k<false, false, true><<<2 * NPAD / 4, 256, 0, stream>>>(
        sxh, csr, rowptr, dinv, nullptr, bufYh);
    mfma_gemm_k<64, 128, 0><<<784, 256, 0, stream>>>(bufYh, Wf1, b1, nullptr, bufH);
    // ---- layer 2: G' = fp16(dinv*(X1@W2)), out = relu(dinv*(sum+self)+b2) ----
    mfma_gemm_k<128, 64, 1><<<784, 256, 0, stream>>>(bufH, Wf2, nullptr, dinv, (_Float16*)gh);
    pull_agg_k<true, true, false><<<2 * NPAD / 4, 256, 0, stream>>>(
        gh, csr, rowptr, dinv, b2, out);
}

// Round 10
// 240.508 us; speedup vs baseline: 8.3845x; 1.1570x over previous
//
#include <hip/hip_runtime.h>
#include <hip/hip_fp16.h>

#define N_NODES 50000
#define N_EDGES 800000
#define NPAD    50176          // 196*256: graph-2 node base, bucket-aligned
#define NBKT    392            // (2*NPAD)/256 buckets of 256 nodes
#define BCAP    6144           // bucket capacity; mean 4082, sigma 64 -> +32 sigma
#define PBN     16             // nodes per pull block (NPAD % PBN == 0)
#define LCAP    1024           // staged csr window cap (mean 256, +48 sigma)
static_assert(N_NODES < 65536, "u16 CSR requires local node ids < 65536");
// LAYOUT RULE: all intermediate buffers indexed by PADDED gid (g*NPAD + i).
// Compaction to the harness's [2*N_NODES,64] output only at pull-2's store.
// Gather/GEMM feature buffers are fp16; all accumulation fp32 (MFMA C=f32).

typedef _Float16 __attribute__((ext_vector_type(8))) half8;
typedef float    __attribute__((ext_vector_type(4))) floatx4;

// Per-block edge-index stride detection (int64 vs int32): odd 32-bit words of
// little-endian int64 with values < 2^31 are all zero.
__device__ __forceinline__ int detect_stride_block(const int* raw1, int* sflag) {
    int odd = 0;
    for (int i = threadIdx.x; i < 2048; i += 256) odd |= raw1[2 * i + 1];
    if (threadIdx.x == 0) *sflag = 0;
    __syncthreads();
    if (odd) atomicOr(sflag, 1);
    __syncthreads();
    return *sflag ? 1 : 2;
}

// ---------------------------------------------------------------------------
// Pass A, SINGLE-PASS: read each edge once; stage packed entry + bucket id in
// LDS while building the per-block bucket histogram; reserve global runs; then
// place from LDS. Entry: (dst_in_bucket << 16) | src_local.
// ---------------------------------------------------------------------------
__global__ __launch_bounds__(256) void binA_k(const int* __restrict__ raw1,
        const int* __restrict__ raw2, unsigned* __restrict__ bcount,
        unsigned* __restrict__ bbuf) {
    __shared__ unsigned ent[8192];           // 32 KB
    __shared__ unsigned short ebkt[8192];    // 16 KB
    __shared__ unsigned hist[NBKT], gofs[NBKT];
    __shared__ int sflag;
    const int stride = detect_stride_block(raw1, &sflag);
    const int tid = threadIdx.x;
    for (int b = tid; b < NBKT; b += 256) hist[b] = 0u;
    __syncthreads();
    const long long e0 = (long long)blockIdx.x * 8192;
    #pragma unroll 4
    for (int it = 0; it < 32; it++) {
        long long e = e0 + it * 256 + tid;
        if (e < 2LL * N_EDGES) {
            int g2 = e >= N_EDGES;
            const int* raw = g2 ? raw2 : raw1;
            long long el = e - (g2 ? N_EDGES : 0);
            int s = raw[el * stride];
            int d = raw[((long long)N_EDGES + el) * stride];
            int gid = g2 * NPAD + d;
            int bkt = gid >> 8;
            int i = it * 256 + tid;
            ent[i] = ((unsigned)(gid & 255) << 16) | (unsigned)s;
            ebkt[i] = (unsigned short)bkt;
            atomicAdd(&hist[bkt], 1u);
        }
    }
    __syncthreads();
    for (int b = tid; b < NBKT; b += 256) {
        unsigned c = hist[b];
        gofs[b] = c ? atomicAdd(&bcount[b], c) : 0u;
    }
    __syncthreads();
    for (int b = tid; b < NBKT; b += 256) hist[b] = 0u;
    __syncthreads();
    #pragma unroll 4
    for (int it = 0; it < 32; it++) {
        long long e = e0 + it * 256 + tid;
        if (e < 2LL * N_EDGES) {
            int i = it * 256 + tid;
            int bkt = (int)ebkt[i];
            unsigned r = atomicAdd(&hist[bkt], 1u);
            unsigned pos = gofs[bkt] + r;
            if (pos < BCAP) bbuf[(size_t)bkt * BCAP + pos] = ent[i];
        }
    }
}

// ---------------------------------------------------------------------------
// Pass B: one block per bucket. Bucket-count scan -> CSR base; per-node
// degree + rowptr + dinv; LDS-cursor CSR scatter; fused fp16 prescale
// sxh = dinv * x for this bucket's 256 nodes.   [R7-verified]
// ---------------------------------------------------------------------------
__global__ __launch_bounds__(256) void buildB_k(const unsigned* __restrict__ bcount,
        const unsigned* __restrict__ bbuf, const float* __restrict__ x1,
        const float* __restrict__ x2, unsigned short* __restrict__ csr,
        int* __restrict__ rowptr, float* __restrict__ dinv,
        __half* __restrict__ sxh) {
    __shared__ unsigned ent[BCAP];
    __shared__ int deg[256], cur[256], tmp[256], tmp2[512];
    __shared__ float sdinv[256];
    const int b = blockIdx.x, tid = threadIdx.x;
    {
        int v = (tid < NBKT) ? (int)bcount[tid] : 0;
        tmp2[tid] = v; tmp2[tid + 256] = (tid + 256 < NBKT) ? (int)bcount[tid + 256] : 0;
        __syncthreads();
        #pragma unroll
        for (int off = 1; off < 512; off <<= 1) {
            int a0 = (tid >= off) ? tmp2[tid - off] : 0;
            int a1 = (tid + 256 >= off) ? tmp2[tid + 256 - off] : 0;
            __syncthreads();
            tmp2[tid] += a0; tmp2[tid + 256] += a1;
            __syncthreads();
        }
    }
    const int cnt = min((int)bcount[b], BCAP);
    const int eb = tmp2[b] - (int)bcount[b];
    for (int i = tid; i < cnt; i += 256) ent[i] = bbuf[(size_t)b * BCAP + i];
    deg[tid] = 0;
    __syncthreads();
    for (int i = tid; i < cnt; i += 256) atomicAdd(&deg[ent[i] >> 16], 1);
    __syncthreads();
    int v = deg[tid];
    tmp[tid] = v;
    __syncthreads();
    #pragma unroll
    for (int off = 1; off < 256; off <<= 1) {
        int add = (tid >= off) ? tmp[tid - off] : 0;
        __syncthreads();
        tmp[tid] += add;
        __syncthreads();
    }
    int excl = tmp[tid] - v;
    cur[tid] = excl;
    const int gid = b * 256 + tid;
    float dv = rsqrtf((float)v + 1.0f);          // +1 self-loop
    rowptr[gid] = eb + excl;
    dinv[gid] = dv;
    sdinv[tid] = dv;
    if (b == NBKT - 1 && tid == 255) rowptr[2 * NPAD] = eb + excl + v;
    __syncthreads();
    for (int i = tid; i < cnt; i += 256) {
        unsigned p = ent[i];
        int pos = atomicAdd(&cur[p >> 16], 1);
        csr[eb + pos] = (unsigned short)(p & 0xFFFFu);
    }
    const int g2 = (b * 256) >= NPAD;
    const float* x = g2 ? x2 : x1;
    const int lbase = b * 256 - (g2 ? NPAD : 0);
    for (int i = tid; i < 256 * 16; i += 256) {
        int n = i >> 4, q = i & 15;
        int local = lbase + n;
        __half2 lo = __floats2half2_rn(0.f, 0.f), hi = lo;
        if (local < N_NODES) {
            float4 vx = *(const float4*)&x[((size_t)local * 16 + q) * 4];
            float dn = sdinv[n];
            lo = __floats2half2_rn(vx.x * dn, vx.y * dn);
            hi = __floats2half2_rn(vx.z * dn, vx.w * dn);
        }
        uint2 u; u.x = *(unsigned*)&lo; u.y = *(unsigned*)&hi;
        *(uint2*)&sxh[(size_t)(b * 256 + n) * 64 + q * 4] = u;
    }
}

// ---------------------------------------------------------------------------
// Pack W into MFMA B-fragment order (fp16):
// Wf[(kc*NT+nt)*512 + lane*8 + j] = W[kc*32 + (lane>>4)*8 + j][nt*16 + (lane&15)]
// ---------------------------------------------------------------------------
__global__ __launch_bounds__(256) void wprep_k(const float* __restrict__ W1,
        const float* __restrict__ W2, _Float16* __restrict__ Wf1,
        _Float16* __restrict__ Wf2) {
    const float* W = blockIdx.x ? W2 : W1;
    _Float16* Wf = blockIdx.x ? Wf2 : Wf1;
    const int M = blockIdx.x ? 64 : 128;
    const int NT = M / 16;
    for (int i = threadIdx.x; i < 8192; i += 256) {   // 16 frags x 512
        int f = i >> 9, r = i & 511;
        int lane = r >> 3, j = r & 7;
        int kc = f / NT, nt = f % NT;
        int k = kc * 32 + (lane >> 4) * 8 + j;
        int m = nt * 16 + (lane & 15);
        Wf[i] = (_Float16)W[k * M + m];
    }
}

// ---------------------------------------------------------------------------
// Pull aggregation, LDS-staged indices: block = 16 nodes; stage rowptr slice,
// dinv slice, and the csr window (<=LCAP u16, coalesced) to LDS. Each wave
// processes 4 nodes; per node: 4 subs x 4 edges in flight, indices from
// ds_read_u16 -> only the gather remains on the global critical path.
// Gather pairs pre-summed fp16 (hadd2) then flushed fp32 [R9-verified].
// Overflow past LCAP (P ~ 0, Poisson(256) tail) reads global csr, guarded.
// ---------------------------------------------------------------------------
template<bool BIAS_RELU, bool COMPACT_OUT, bool OUT_HALF>
__global__ __launch_bounds__(256) void pull_agg_k(const __half* __restrict__ sh,
        const unsigned short* __restrict__ csr, const int* __restrict__ rowptr,
        const float* __restrict__ dinv, const float* __restrict__ bias,
        void* __restrict__ outv) {
    __shared__ unsigned short lcsr[LCAP];
    __shared__ int lrp[PBN + 1];
    __shared__ float ldv[PBN];
    const int tid = threadIdx.x;
    const int n0 = blockIdx.x * PBN;             // padded node base (no straddle)
    const int g2 = n0 >= NPAD;
    const int gbase = g2 ? NPAD : 0;
    if (tid <= PBN) lrp[tid] = rowptr[n0 + tid];
    if (tid < PBN)  ldv[tid] = dinv[n0 + tid];
    __syncthreads();
    const int wb = lrp[0];
    const int wcnt = min(lrp[PBN] - wb, LCAP);
    for (int i = tid; i < wcnt; i += 256) lcsr[i] = csr[wb + i];
    __syncthreads();
    const int wv = tid >> 6, lane = tid & 63;
    const int sub = lane >> 4, fl = lane & 15;
    float4 bv;
    if (BIAS_RELU) bv = *(const float4*)&bias[fl * 4];
    for (int r = 0; r < 4; r++) {
        const int n = wv * 4 + r;
        const int d = n0 + n;
        const int jfull = lrp[n + 1] - wb;
        const int jb = min(lrp[n] - wb, wcnt), je = min(jfull, wcnt);
        float4 acc = {0.f, 0.f, 0.f, 0.f};
        int j = jb;
        for (; j + 16 <= je; j += 16) {
            int s0 = (int)lcsr[j      + sub] + gbase;
            int s1 = (int)lcsr[j + 4  + sub] + gbase;
            int s2 = (int)lcsr[j + 8  + sub] + gbase;
            int s3 = (int)lcsr[j + 12 + sub] + gbase;
            uint2 u0 = *(const uint2*)&sh[(size_t)s0 * 64 + fl * 4];
            uint2 u1 = *(const uint2*)&sh[(size_t)s1 * 64 + fl * 4];
            uint2 u2 = *(const uint2*)&sh[(size_t)s2 * 64 + fl * 4];
            uint2 u3 = *(const uint2*)&sh[(size_t)s3 * 64 + fl * 4];
            __half2 pa = __hadd2(*(__half2*)&u0.x, *(__half2*)&u1.x);
            __half2 pb = __hadd2(*(__half2*)&u0.y, *(__half2*)&u1.y);
            __half2 pc = __hadd2(*(__half2*)&u2.x, *(__half2*)&u3.x);
            __half2 pd = __hadd2(*(__half2*)&u2.y, *(__half2*)&u3.y);
            float2 fa = __half22float2(pa), fb = __half22float2(pb);
            float2 fc = __half22float2(pc), fd = __half22float2(pd);
            acc.x += fa.x + fc.x; acc.y += fa.y + fc.y;
            acc.z += fb.x + fd.x; acc.w += fb.y + fd.y;
        }
        for (; j < je; j += 4) {
            int idx = j + sub;
            int ii = (idx < je) ? idx : jb;          // safe addr (row nonempty here)
            int s = (int)lcsr[ii] + gbase;
            uint2 u = *(const uint2*)&sh[(size_t)s * 64 + fl * 4];
            if (idx < je) {
                float2 f0 = __half22float2(*(__half2*)&u.x);
                float2 f1 = __half22float2(*(__half2*)&u.y);
                acc.x += f0.x; acc.y += f0.y; acc.z += f1.x; acc.w += f1.y;
            }
        }
        for (int j2 = je; j2 < jfull; j2 += 4) {     // overflow: global, guarded
            int idx = j2 + sub;
            if (idx < jfull) {
                int s = (int)csr[wb + idx] + gbase;
                uint2 u = *(const uint2*)&sh[(size_t)s * 64 + fl * 4];
                float2 f0 = __half22float2(*(__half2*)&u.x);
                float2 f1 = __half22float2(*(__half2*)&u.y);
                acc.x += f0.x; acc.y += f0.y; acc.z += f1.x; acc.w += f1.y;
            }
        }
        acc.x += __shfl_xor(acc.x, 16); acc.y += __shfl_xor(acc.y, 16);
        acc.z += __shfl_xor(acc.z, 16); acc.w += __shfl_xor(acc.w, 16);
        acc.x += __shfl_xor(acc.x, 32); acc.y += __shfl_xor(acc.y, 32);
        acc.z += __shfl_xor(acc.z, 32); acc.w += __shfl_xor(acc.w, 32);
        uint2 su = *(const uint2*)&sh[(size_t)d * 64 + fl * 4];
        float2 sf0 = __half22float2(*(__half2*)&su.x);
        float2 sf1 = __half22float2(*(__half2*)&su.y);
        float dv = ldv[n];
        float4 o;
        o.x = (acc.x + sf0.x) * dv;
        o.y = (acc.y + sf0.y) * dv;
        o.z = (acc.z + sf1.x) * dv;
        o.w = (acc.w + sf1.y) * dv;
        if (BIAS_RELU) {
            o.x = fmaxf(o.x + bv.x, 0.f);
            o.y = fmaxf(o.y + bv.y, 0.f);
            o.z = fmaxf(o.z + bv.z, 0.f);
            o.w = fmaxf(o.w + bv.w, 0.f);
        }
        if (sub == 0) {
            if (OUT_HALF) {
                __half2 lo = __floats2half2_rn(o.x, o.y);
                __half2 hi = __floats2half2_rn(o.z, o.w);
                uint2 u; u.x = *(unsigned*)&lo; u.y = *(unsigned*)&hi;
                *(uint2*)&((__half*)outv)[(size_t)d * 64 + fl * 4] = u;  // padded
            } else {
                int local = d - gbase;
                if (!COMPACT_OUT) {
                    *(float4*)&((float*)outv)[(size_t)d * 64 + fl * 4] = o;
                } else if (local < N_NODES) {
                    size_t orow = (size_t)(g2 ? N_NODES + local : local);
                    *(float4*)&((float*)outv)[orow * 64 + fl * 4] = o;
                }
            }
        }
    }
}

// ---------------------------------------------------------------------------
// MFMA GEMM: H(fp16) = epi(X(fp16) @ W). v_mfma_f32_16x16x32_f16.
// A frag: contiguous half8 per lane from row-major X. B frags from wprep.
// C/D: col=lane&15, row=(lane>>4)*4+reg [HW-verified]. Grid 784 exact.
// EPI 0: relu(v + bias[col]). EPI 1: v * dinv[row] (prescale for pull-2).
// ---------------------------------------------------------------------------
template<int K, int M, int EPI>
__global__ __launch_bounds__(256) void mfma_gemm_k(const _Float16* __restrict__ X,
        const _Float16* __restrict__ Wf, const float* __restrict__ bias,
        const float* __restrict__ dinv, _Float16* __restrict__ H) {
    constexpr int KC = K / 32, NT = M / 16, RT = 2;
    const int tid = threadIdx.x;
    const int wv = tid >> 6, lane = tid & 63;
    const int quad = lane >> 4, c = lane & 15;
    const int row0 = blockIdx.x * (4 * RT * 16) + wv * (RT * 16);
    half8 bf[KC][NT];
    #pragma unroll
    for (int kc = 0; kc < KC; kc++)
        #pragma unroll
        for (int nt = 0; nt < NT; nt++)
            bf[kc][nt] = *(const half8*)&Wf[((kc * NT + nt) * 64 + lane) * 8];
    floatx4 acc[RT][NT] = {};
    #pragma unroll
    for (int rt = 0; rt < RT; rt++) {
        half8 a[KC];
        #pragma unroll
        for (int kc = 0; kc < KC; kc++)
            a[kc] = *(const half8*)&X[(size_t)(row0 + rt * 16 + c) * K + kc * 32 + quad * 8];
        #pragma unroll
        for (int nt = 0; nt < NT; nt++)
            #pragma unroll
            for (int kc = 0; kc < KC; kc++)
                acc[rt][nt] = __builtin_amdgcn_mfma_f32_16x16x32_f16(
                    a[kc], bf[kc][nt], acc[rt][nt], 0, 0, 0);
    }
    float bv[NT];
    if (EPI == 0) {
        #pragma unroll
        for (int nt = 0; nt < NT; nt++) bv[nt] = bias[nt * 16 + c];
    }
    #pragma unroll
    for (int rt = 0; rt < RT; rt++) {
        const int rbase = row0 + rt * 16 + quad * 4;
        float4 dvv = {0.f, 0.f, 0.f, 0.f};
        if (EPI == 1) dvv = *(const float4*)&dinv[rbase];
        #pragma unroll
        for (int nt = 0; nt < NT; nt++)
            #pragma unroll
            for (int reg = 0; reg < 4; reg++) {
                float v = acc[rt][nt][reg];
                if (EPI == 0) v = fmaxf(v + bv[nt], 0.f);
                else          v *= ((const float*)&dvv)[reg];
                H[(size_t)(rbase + reg) * M + nt * 16 + c] = (_Float16)v;
            }
    }
}

extern "C" void kernel_launch(void* const* d_in, const int* in_sizes, int n_in,
                              void* d_out, int out_size, void* d_ws, size_t ws_size,
                              hipStream_t stream) {
    const float* x1 = (const float*)d_in[0];
    const int*   e1 = (const int*)d_in[1];
    const float* x2 = (const float*)d_in[2];
    const int*   e2 = (const int*)d_in[3];
    const float* W1 = (const float*)d_in[4];
    const float* b1 = (const float*)d_in[5];
    const float* W2 = (const float*)d_in[6];
    const float* b2 = (const float*)d_in[7];
    float* out = (float*)d_out;

    // Workspace (~70 MB), 256 B-aligned chunks.
    char* p = (char*)d_ws;
    auto alloc = [&](size_t bytes) { char* r = p; p += (bytes + 255) & ~(size_t)255; return r; };
    unsigned* bcount = (unsigned*)alloc(NBKT * 4);
    float*    dinv   = (float*)alloc((size_t)2 * NPAD * 4);
    int*      rowptr = (int*)alloc(((size_t)2 * NPAD + 1) * 4);
    unsigned* bbuf   = (unsigned*)alloc((size_t)NBKT * BCAP * 4);
    unsigned short* csr = (unsigned short*)alloc((size_t)2 * N_EDGES * 2);
    __half*   sxh    = (__half*)alloc((size_t)2 * NPAD * 64 * 2);    // fp16 feats
    _Float16* bufYh  = (_Float16*)alloc((size_t)2 * NPAD * 64 * 2);  // fp16 Y
    _Float16* bufH   = (_Float16*)alloc((size_t)2 * NPAD * 128 * 2); // fp16 X1
    _Float16* Wf1    = (_Float16*)alloc(8192 * 2);
    _Float16* Wf2    = (_Float16*)alloc(8192 * 2);
    __half*   gh     = sxh;   // alias: sxh dead after pull-1; gemm-2 writes gh

    // ---- CSR build + dinv + fp16 prescale + W fragment pack ----
    hipMemsetAsync(bcount, 0, NBKT * 4, stream);
    binA_k<<<196, 256, 0, stream>>>(e1, e2, bcount, bbuf);
    buildB_k<<<NBKT, 256, 0, stream>>>(bcount, bbuf, x1, x2, csr, rowptr, dinv, sxh);
    wprep_k<<<2, 256, 0, stream>>>(W1, W2, Wf1, Wf2);

    // ---- layer 1: Y = A_hat @ X (fp16), X1 = fp16(relu(Y@W1 + b1)) ----
    pull_agg_k<false, false, true><<<2 * NPAD / PBN, 256, 0, stream>>>(
        sxh, csr, rowptr, dinv, nullptr, bufYh);
    mfma_gemm_k<64, 128, 0><<<784, 256, 0, stream>>>(bufYh, Wf1, b1, nullptr, bufH);
    // ---- layer 2: G' = fp16(dinv*(X1@W2)), out = relu(dinv*(sum+self)+b2) ----
    mfma_gemm_k<128, 64, 1><<<784, 256, 0, stream>>>(bufH, Wf2, nullptr, dinv, (_Float16*)gh);
    pull_agg_k<true, true, false><<<2 * NPAD / PBN, 256, 0, stream>>>(
        gh, csr, rowptr, dinv, b2, out);
}

// Round 11
// 226.623 us; speedup vs baseline: 8.8983x; 1.0613x over previous
//
#include <hip/hip_runtime.h>
#include <hip/hip_fp16.h>

#define N_NODES 50000
#define N_EDGES 800000
#define NPAD    50176          // 196*256: graph-2 node base, bucket-aligned
#define NBKT    392            // (2*NPAD)/256 buckets of 256 nodes
#define BCAP    6144           // bucket capacity; mean 4082, sigma 64 -> +32 sigma
#define PBN     16             // nodes per pull block (NPAD % PBN == 0)
#define LCAP    1024           // staged csr window cap (mean 256, +48 sigma)
#define X1S     136            // LDS X1 stride (halfs): 272 B rows, 16B-aligned
static_assert(N_NODES < 65536, "u16 CSR requires local node ids < 65536");
// LAYOUT RULE: all intermediate buffers indexed by PADDED gid (g*NPAD + i).
// Compaction to the harness's [2*N_NODES,64] output only at pull-2's store.
// Gather/GEMM feature buffers are fp16; all accumulation fp32 (MFMA C=f32).

typedef _Float16 __attribute__((ext_vector_type(8))) half8;
typedef float    __attribute__((ext_vector_type(4))) floatx4;

// Per-block edge-index stride detection (int64 vs int32): odd 32-bit words of
// little-endian int64 with values < 2^31 are all zero.
__device__ __forceinline__ int detect_stride_block(const int* raw1, int* sflag) {
    int odd = 0;
    for (int i = threadIdx.x; i < 2048; i += 256) odd |= raw1[2 * i + 1];
    if (threadIdx.x == 0) *sflag = 0;
    __syncthreads();
    if (odd) atomicOr(sflag, 1);
    __syncthreads();
    return *sflag ? 1 : 2;
}

// ---------------------------------------------------------------------------
// Pass A, SINGLE-PASS, 392 edge-blocks x 4096 edges (higher occupancy than
// 196x8192: 27 KB LDS): stage packed entry + bucket id in LDS while building
// the per-block bucket histogram; reserve global runs; place from LDS.
// Entry: (dst_in_bucket << 16) | src_local.
// Blocks 392/393 instead pack W1/W2 into MFMA B-fragment order:
// Wf[(kc*NT+nt)*512 + lane*8 + j] = W[kc*32+(lane>>4)*8+j][nt*16+(lane&15)].
// ---------------------------------------------------------------------------
__global__ __launch_bounds__(256) void binA_k(const int* __restrict__ raw1,
        const int* __restrict__ raw2, const float* __restrict__ W1,
        const float* __restrict__ W2, unsigned* __restrict__ bcount,
        unsigned* __restrict__ bbuf, _Float16* __restrict__ Wf1,
        _Float16* __restrict__ Wf2) {
    if (blockIdx.x >= 392) {                 // fused wprep
        const int wsel = blockIdx.x - 392;
        const float* W = wsel ? W2 : W1;
        _Float16* Wf = wsel ? Wf2 : Wf1;
        const int M = wsel ? 64 : 128;
        const int NT = M / 16;
        for (int i = threadIdx.x; i < 8192; i += 256) {   // 16 frags x 512
            int f = i >> 9, r = i & 511;
            int lane = r >> 3, j = r & 7;
            int kc = f / NT, nt = f % NT;
            int k = kc * 32 + (lane >> 4) * 8 + j;
            int m = nt * 16 + (lane & 15);
            Wf[i] = (_Float16)W[k * M + m];
        }
        return;
    }
    __shared__ unsigned ent[4096];           // 16 KB
    __shared__ unsigned short ebkt[4096];    // 8 KB
    __shared__ unsigned hist[NBKT], gofs[NBKT];
    __shared__ int sflag;
    const int stride = detect_stride_block(raw1, &sflag);
    const int tid = threadIdx.x;
    for (int b = tid; b < NBKT; b += 256) hist[b] = 0u;
    __syncthreads();
    const long long e0 = (long long)blockIdx.x * 4096;
    #pragma unroll 4
    for (int it = 0; it < 16; it++) {
        long long e = e0 + it * 256 + tid;
        if (e < 2LL * N_EDGES) {
            int g2 = e >= N_EDGES;
            const int* raw = g2 ? raw2 : raw1;
            long long el = e - (g2 ? N_EDGES : 0);
            int s = raw[el * stride];
            int d = raw[((long long)N_EDGES + el) * stride];
            int gid = g2 * NPAD + d;
            int bkt = gid >> 8;
            int i = it * 256 + tid;
            ent[i] = ((unsigned)(gid & 255) << 16) | (unsigned)s;
            ebkt[i] = (unsigned short)bkt;
            atomicAdd(&hist[bkt], 1u);
        }
    }
    __syncthreads();
    for (int b = tid; b < NBKT; b += 256) {
        unsigned c = hist[b];
        gofs[b] = c ? atomicAdd(&bcount[b], c) : 0u;
    }
    __syncthreads();
    for (int b = tid; b < NBKT; b += 256) hist[b] = 0u;
    __syncthreads();
    #pragma unroll 4
    for (int it = 0; it < 16; it++) {
        long long e = e0 + it * 256 + tid;
        if (e < 2LL * N_EDGES) {
            int i = it * 256 + tid;
            int bkt = (int)ebkt[i];
            unsigned r = atomicAdd(&hist[bkt], 1u);
            unsigned pos = gofs[bkt] + r;
            if (pos < BCAP) bbuf[(size_t)bkt * BCAP + pos] = ent[i];
        }
    }
}

// ---------------------------------------------------------------------------
// Pass B: one block per bucket. Bucket-count scan -> CSR base; per-node
// degree + rowptr + dinv; LDS-cursor CSR scatter; fused fp16 prescale
// sxh = dinv * x for this bucket's 256 nodes.   [R7-verified]
// ---------------------------------------------------------------------------
__global__ __launch_bounds__(256) void buildB_k(const unsigned* __restrict__ bcount,
        const unsigned* __restrict__ bbuf, const float* __restrict__ x1,
        const float* __restrict__ x2, unsigned short* __restrict__ csr,
        int* __restrict__ rowptr, float* __restrict__ dinv,
        __half* __restrict__ sxh) {
    __shared__ unsigned ent[BCAP];
    __shared__ int deg[256], cur[256], tmp[256], tmp2[512];
    __shared__ float sdinv[256];
    const int b = blockIdx.x, tid = threadIdx.x;
    {
        int v = (tid < NBKT) ? (int)bcount[tid] : 0;
        tmp2[tid] = v; tmp2[tid + 256] = (tid + 256 < NBKT) ? (int)bcount[tid + 256] : 0;
        __syncthreads();
        #pragma unroll
        for (int off = 1; off < 512; off <<= 1) {
            int a0 = (tid >= off) ? tmp2[tid - off] : 0;
            int a1 = (tid + 256 >= off) ? tmp2[tid + 256 - off] : 0;
            __syncthreads();
            tmp2[tid] += a0; tmp2[tid + 256] += a1;
            __syncthreads();
        }
    }
    const int cnt = min((int)bcount[b], BCAP);
    const int eb = tmp2[b] - (int)bcount[b];
    for (int i = tid; i < cnt; i += 256) ent[i] = bbuf[(size_t)b * BCAP + i];
    deg[tid] = 0;
    __syncthreads();
    for (int i = tid; i < cnt; i += 256) atomicAdd(&deg[ent[i] >> 16], 1);
    __syncthreads();
    int v = deg[tid];
    tmp[tid] = v;
    __syncthreads();
    #pragma unroll
    for (int off = 1; off < 256; off <<= 1) {
        int add = (tid >= off) ? tmp[tid - off] : 0;
        __syncthreads();
        tmp[tid] += add;
        __syncthreads();
    }
    int excl = tmp[tid] - v;
    cur[tid] = excl;
    const int gid = b * 256 + tid;
    float dv = rsqrtf((float)v + 1.0f);          // +1 self-loop
    rowptr[gid] = eb + excl;
    dinv[gid] = dv;
    sdinv[tid] = dv;
    if (b == NBKT - 1 && tid == 255) rowptr[2 * NPAD] = eb + excl + v;
    __syncthreads();
    for (int i = tid; i < cnt; i += 256) {
        unsigned p = ent[i];
        int pos = atomicAdd(&cur[p >> 16], 1);
        csr[eb + pos] = (unsigned short)(p & 0xFFFFu);
    }
    const int g2 = (b * 256) >= NPAD;
    const float* x = g2 ? x2 : x1;
    const int lbase = b * 256 - (g2 ? NPAD : 0);
    for (int i = tid; i < 256 * 16; i += 256) {
        int n = i >> 4, q = i & 15;
        int local = lbase + n;
        __half2 lo = __floats2half2_rn(0.f, 0.f), hi = lo;
        if (local < N_NODES) {
            float4 vx = *(const float4*)&x[((size_t)local * 16 + q) * 4];
            float dn = sdinv[n];
            lo = __floats2half2_rn(vx.x * dn, vx.y * dn);
            hi = __floats2half2_rn(vx.z * dn, vx.w * dn);
        }
        uint2 u; u.x = *(unsigned*)&lo; u.y = *(unsigned*)&hi;
        *(uint2*)&sxh[(size_t)(b * 256 + n) * 64 + q * 4] = u;
    }
}

// ---------------------------------------------------------------------------
// Pull aggregation, LDS-staged indices [R10-verified]: block = 16 nodes;
// stage rowptr slice, dinv slice, csr window (<=LCAP u16) to LDS. Each wave
// processes 4 nodes; indices via ds_read -> only gathers on the global
// critical path. Gather pairs pre-summed fp16 then flushed fp32.
// ---------------------------------------------------------------------------
template<bool BIAS_RELU, bool COMPACT_OUT, bool OUT_HALF>
__global__ __launch_bounds__(256) void pull_agg_k(const __half* __restrict__ sh,
        const unsigned short* __restrict__ csr, const int* __restrict__ rowptr,
        const float* __restrict__ dinv, const float* __restrict__ bias,
        void* __restrict__ outv) {
    __shared__ unsigned short lcsr[LCAP];
    __shared__ int lrp[PBN + 1];
    __shared__ float ldv[PBN];
    const int tid = threadIdx.x;
    const int n0 = blockIdx.x * PBN;             // padded node base (no straddle)
    const int g2 = n0 >= NPAD;
    const int gbase = g2 ? NPAD : 0;
    if (tid <= PBN) lrp[tid] = rowptr[n0 + tid];
    if (tid < PBN)  ldv[tid] = dinv[n0 + tid];
    __syncthreads();
    const int wb = lrp[0];
    const int wcnt = min(lrp[PBN] - wb, LCAP);
    for (int i = tid; i < wcnt; i += 256) lcsr[i] = csr[wb + i];
    __syncthreads();
    const int wv = tid >> 6, lane = tid & 63;
    const int sub = lane >> 4, fl = lane & 15;
    float4 bv;
    if (BIAS_RELU) bv = *(const float4*)&bias[fl * 4];
    for (int r = 0; r < 4; r++) {
        const int n = wv * 4 + r;
        const int d = n0 + n;
        const int jfull = lrp[n + 1] - wb;
        const int jb = min(lrp[n] - wb, wcnt), je = min(jfull, wcnt);
        float4 acc = {0.f, 0.f, 0.f, 0.f};
        int j = jb;
        for (; j + 16 <= je; j += 16) {
            int s0 = (int)lcsr[j      + sub] + gbase;
            int s1 = (int)lcsr[j + 4  + sub] + gbase;
            int s2 = (int)lcsr[j + 8  + sub] + gbase;
            int s3 = (int)lcsr[j + 12 + sub] + gbase;
            uint2 u0 = *(const uint2*)&sh[(size_t)s0 * 64 + fl * 4];
            uint2 u1 = *(const uint2*)&sh[(size_t)s1 * 64 + fl * 4];
            uint2 u2 = *(const uint2*)&sh[(size_t)s2 * 64 + fl * 4];
            uint2 u3 = *(const uint2*)&sh[(size_t)s3 * 64 + fl * 4];
            __half2 pa = __hadd2(*(__half2*)&u0.x, *(__half2*)&u1.x);
            __half2 pb = __hadd2(*(__half2*)&u0.y, *(__half2*)&u1.y);
            __half2 pc = __hadd2(*(__half2*)&u2.x, *(__half2*)&u3.x);
            __half2 pd = __hadd2(*(__half2*)&u2.y, *(__half2*)&u3.y);
            float2 fa = __half22float2(pa), fb = __half22float2(pb);
            float2 fc = __half22float2(pc), fd = __half22float2(pd);
            acc.x += fa.x + fc.x; acc.y += fa.y + fc.y;
            acc.z += fb.x + fd.x; acc.w += fb.y + fd.y;
        }
        for (; j < je; j += 4) {
            int idx = j + sub;
            int ii = (idx < je) ? idx : jb;          // safe addr (row nonempty here)
            int s = (int)lcsr[ii] + gbase;
            uint2 u = *(const uint2*)&sh[(size_t)s * 64 + fl * 4];
            if (idx < je) {
                float2 f0 = __half22float2(*(__half2*)&u.x);
                float2 f1 = __half22float2(*(__half2*)&u.y);
                acc.x += f0.x; acc.y += f0.y; acc.z += f1.x; acc.w += f1.y;
            }
        }
        for (int j2 = je; j2 < jfull; j2 += 4) {     // overflow: global, guarded
            int idx = j2 + sub;
            if (idx < jfull) {
                int s = (int)csr[wb + idx] + gbase;
                uint2 u = *(const uint2*)&sh[(size_t)s * 64 + fl * 4];
                float2 f0 = __half22float2(*(__half2*)&u.x);
                float2 f1 = __half22float2(*(__half2*)&u.y);
                acc.x += f0.x; acc.y += f0.y; acc.z += f1.x; acc.w += f1.y;
            }
        }
        acc.x += __shfl_xor(acc.x, 16); acc.y += __shfl_xor(acc.y, 16);
        acc.z += __shfl_xor(acc.z, 16); acc.w += __shfl_xor(acc.w, 16);
        acc.x += __shfl_xor(acc.x, 32); acc.y += __shfl_xor(acc.y, 32);
        acc.z += __shfl_xor(acc.z, 32); acc.w += __shfl_xor(acc.w, 32);
        uint2 su = *(const uint2*)&sh[(size_t)d * 64 + fl * 4];
        float2 sf0 = __half22float2(*(__half2*)&su.x);
        float2 sf1 = __half22float2(*(__half2*)&su.y);
        float dv = ldv[n];
        float4 o;
        o.x = (acc.x + sf0.x) * dv;
        o.y = (acc.y + sf0.y) * dv;
        o.z = (acc.z + sf1.x) * dv;
        o.w = (acc.w + sf1.y) * dv;
        if (BIAS_RELU) {
            o.x = fmaxf(o.x + bv.x, 0.f);
            o.y = fmaxf(o.y + bv.y, 0.f);
            o.z = fmaxf(o.z + bv.z, 0.f);
            o.w = fmaxf(o.w + bv.w, 0.f);
        }
        if (sub == 0) {
            if (OUT_HALF) {
                __half2 lo = __floats2half2_rn(o.x, o.y);
                __half2 hi = __floats2half2_rn(o.z, o.w);
                uint2 u; u.x = *(unsigned*)&lo; u.y = *(unsigned*)&hi;
                *(uint2*)&((__half*)outv)[(size_t)d * 64 + fl * 4] = u;  // padded
            } else {
                int local = d - gbase;
                if (!COMPACT_OUT) {
                    *(float4*)&((float*)outv)[(size_t)d * 64 + fl * 4] = o;
                } else if (local < N_NODES) {
                    size_t orow = (size_t)(g2 ? N_NODES + local : local);
                    *(float4*)&((float*)outv)[orow * 64 + fl * 4] = o;
                }
            }
        }
    }
}

// ---------------------------------------------------------------------------
// FUSED double MFMA GEMM: GH = dinv * (relu(Y@W1 + b1) @ W2), per 128-row
// block, X1 routed through LDS (row-major, stride X1S=136 halfs: 272 B rows
// keep ds_read_b128 aligned; write aliasing <=4-way, read <=2-way).
// Y rows are block-local -> no inter-block dependency. Grid 784 exact.
// C/D layout col=lane&15, row=(lane>>4)*4+reg [HW-verified, R9].
// ---------------------------------------------------------------------------
__global__ __launch_bounds__(256) void gemm12_k(const _Float16* __restrict__ Y,
        const _Float16* __restrict__ Wf1, const float* __restrict__ b1,
        const _Float16* __restrict__ Wf2, const float* __restrict__ dinv,
        _Float16* __restrict__ GH) {
    __shared__ _Float16 X1l[128 * X1S];      // 34.8 KB
    const int tid = threadIdx.x;
    const int wv = tid >> 6, lane = tid & 63;
    const int quad = lane >> 4, c = lane & 15;
    const int lrow0 = wv * 32;               // wave's 32 local rows
    const int grow0 = blockIdx.x * 128 + lrow0;
    // ---- phase 1: X1 = relu(Y @ W1 + b1) -> LDS ----
    {
        half8 bf[2][8];                      // K=64 (KC=2), M=128 (NT=8)
        #pragma unroll
        for (int kc = 0; kc < 2; kc++)
            #pragma unroll
            for (int nt = 0; nt < 8; nt++)
                bf[kc][nt] = *(const half8*)&Wf1[((kc * 8 + nt) * 64 + lane) * 8];
        floatx4 acc[2][8] = {};
        #pragma unroll
        for (int rt = 0; rt < 2; rt++) {
            half8 a[2];
            #pragma unroll
            for (int kc = 0; kc < 2; kc++)
                a[kc] = *(const half8*)&Y[(size_t)(grow0 + rt * 16 + c) * 64 + kc * 32 + quad * 8];
            #pragma unroll
            for (int nt = 0; nt < 8; nt++)
                #pragma unroll
                for (int kc = 0; kc < 2; kc++)
                    acc[rt][nt] = __builtin_amdgcn_mfma_f32_16x16x32_f16(
                        a[kc], bf[kc][nt], acc[rt][nt], 0, 0, 0);
        }
        float bv[8];
        #pragma unroll
        for (int nt = 0; nt < 8; nt++) bv[nt] = b1[nt * 16 + c];
        #pragma unroll
        for (int rt = 0; rt < 2; rt++)
            #pragma unroll
            for (int nt = 0; nt < 8; nt++)
                #pragma unroll
                for (int reg = 0; reg < 4; reg++) {
                    float v = fmaxf(acc[rt][nt][reg] + bv[nt], 0.f);
                    X1l[(lrow0 + rt * 16 + quad * 4 + reg) * X1S + nt * 16 + c] = (_Float16)v;
                }
    }
    __syncthreads();
    // ---- phase 2: GH = dinv * (X1 @ W2) ----
    {
        half8 bf[4][4];                      // K=128 (KC=4), M=64 (NT=4)
        #pragma unroll
        for (int kc = 0; kc < 4; kc++)
            #pragma unroll
            for (int nt = 0; nt < 4; nt++)
                bf[kc][nt] = *(const half8*)&Wf2[((kc * 4 + nt) * 64 + lane) * 8];
        floatx4 acc[2][4] = {};
        #pragma unroll
        for (int rt = 0; rt < 2; rt++) {
            half8 a[4];
            #pragma unroll
            for (int kc = 0; kc < 4; kc++)
                a[kc] = *(const half8*)&X1l[(lrow0 + rt * 16 + c) * X1S + kc * 32 + quad * 8];
            #pragma unroll
            for (int nt = 0; nt < 4; nt++)
                #pragma unroll
                for (int kc = 0; kc < 4; kc++)
                    acc[rt][nt] = __builtin_amdgcn_mfma_f32_16x16x32_f16(
                        a[kc], bf[kc][nt], acc[rt][nt], 0, 0, 0);
        }
        #pragma unroll
        for (int rt = 0; rt < 2; rt++) {
            const int rbase = grow0 + rt * 16 + quad * 4;
            float4 dvv = *(const float4*)&dinv[rbase];
            #pragma unroll
            for (int nt = 0; nt < 4; nt++)
                #pragma unroll
                for (int reg = 0; reg < 4; reg++) {
                    float v = acc[rt][nt][reg] * ((const float*)&dvv)[reg];
                    GH[(size_t)(rbase + reg) * 64 + nt * 16 + c] = (_Float16)v;
                }
        }
    }
}

extern "C" void kernel_launch(void* const* d_in, const int* in_sizes, int n_in,
                              void* d_out, int out_size, void* d_ws, size_t ws_size,
                              hipStream_t stream) {
    const float* x1 = (const float*)d_in[0];
    const int*   e1 = (const int*)d_in[1];
    const float* x2 = (const float*)d_in[2];
    const int*   e2 = (const int*)d_in[3];
    const float* W1 = (const float*)d_in[4];
    const float* b1 = (const float*)d_in[5];
    const float* W2 = (const float*)d_in[6];
    const float* b2 = (const float*)d_in[7];
    float* out = (float*)d_out;

    // Workspace (~45 MB), 256 B-aligned chunks.
    char* p = (char*)d_ws;
    auto alloc = [&](size_t bytes) { char* r = p; p += (bytes + 255) & ~(size_t)255; return r; };
    unsigned* bcount = (unsigned*)alloc(NBKT * 4);
    float*    dinv   = (float*)alloc((size_t)2 * NPAD * 4);
    int*      rowptr = (int*)alloc(((size_t)2 * NPAD + 1) * 4);
    unsigned* bbuf   = (unsigned*)alloc((size_t)NBKT * BCAP * 4);
    unsigned short* csr = (unsigned short*)alloc((size_t)2 * N_EDGES * 2);
    __half*   sxh    = (__half*)alloc((size_t)2 * NPAD * 64 * 2);    // fp16 feats
    _Float16* bufYh  = (_Float16*)alloc((size_t)2 * NPAD * 64 * 2);  // fp16 Y
    _Float16* Wf1    = (_Float16*)alloc(8192 * 2);
    _Float16* Wf2    = (_Float16*)alloc(8192 * 2);
    __half*   gh     = sxh;   // alias: sxh dead after pull-1; gemm12 writes gh

    // ---- CSR build + dinv + fp16 prescale + W fragment pack (fused) ----
    hipMemsetAsync(bcount, 0, NBKT * 4, stream);
    binA_k<<<394, 256, 0, stream>>>(e1, e2, W1, W2, bcount, bbuf, Wf1, Wf2);
    buildB_k<<<NBKT, 256, 0, stream>>>(bcount, bbuf, x1, x2, csr, rowptr, dinv, sxh);

    // ---- layer 1 agg: Y = A_hat @ X (fp16) ----
    pull_agg_k<false, false, true><<<2 * NPAD / PBN, 256, 0, stream>>>(
        sxh, csr, rowptr, dinv, nullptr, bufYh);
    // ---- fused GEMMs: G' = fp16(dinv * (relu(Y@W1+b1) @ W2)) ----
    gemm12_k<<<784, 256, 0, stream>>>(bufYh, Wf1, b1, Wf2, dinv, (_Float16*)gh);
    // ---- layer 2 agg + epilogue: out = relu(dinv*(sum+self)+b2) ----
    pull_agg_k<true, true, false><<<2 * NPAD / PBN, 256, 0, stream>>>(
        gh, csr, rowptr, dinv, b2, out);
}

// Round 12
// 220.988 us; speedup vs baseline: 9.1251x; 1.0255x over previous
//
#include <hip/hip_runtime.h>
#include <hip/hip_fp16.h>

#define N_NODES 50000
#define N_EDGES 800000
#define NPAD    50176          // 196*256: graph-2 node base, bucket-aligned
#define NBKT    392            // (2*NPAD)/256 buckets of 256 nodes
#define BCAP    6144           // bucket capacity; mean 4082, sigma 64 -> +32 sigma
#define PBN     16             // nodes per pull block (NPAD % PBN == 0)
#define LCAP    1024           // staged csr window cap (mean 256, +48 sigma)
#define X1S     136            // LDS X1 stride (halfs): 272 B rows, 16B-aligned
static_assert(N_NODES < 65536, "u16 CSR requires local node ids < 65536");
// LAYOUT RULE: all intermediate buffers indexed by PADDED gid (g*NPAD + i).
// Compaction to the harness's [2*N_NODES,64] output only at pull-2's store.
// Gather/GEMM feature buffers are fp16; all accumulation fp32 (MFMA C=f32).

typedef _Float16 __attribute__((ext_vector_type(8))) half8;
typedef float    __attribute__((ext_vector_type(4))) floatx4;

// Per-block edge-index stride detection (int64 vs int32): odd 32-bit words of
// little-endian int64 with values < 2^31 are all zero.
__device__ __forceinline__ int detect_stride_block(const int* raw1, int* sflag) {
    int odd = 0;
    for (int i = threadIdx.x; i < 2048; i += 256) odd |= raw1[2 * i + 1];
    if (threadIdx.x == 0) *sflag = 0;
    __syncthreads();
    if (odd) atomicOr(sflag, 1);
    __syncthreads();
    return *sflag ? 1 : 2;
}

// ---------------------------------------------------------------------------
// Pass A, SINGLE-PASS, 392 edge-blocks x 4096 edges: stage packed entry +
// bucket id in LDS while building the per-block bucket histogram; reserve
// global runs; place from LDS. Entry: (dst_in_bucket << 16) | src_local.
// Blocks 392/393 pack W1/W2 into MFMA B-fragment order:
// Wf[(kc*NT+nt)*512 + lane*8 + j] = W[kc*32+(lane>>4)*8+j][nt*16+(lane&15)].
// ---------------------------------------------------------------------------
__global__ __launch_bounds__(256) void binA_k(const int* __restrict__ raw1,
        const int* __restrict__ raw2, const float* __restrict__ W1,
        const float* __restrict__ W2, unsigned* __restrict__ bcount,
        unsigned* __restrict__ bbuf, _Float16* __restrict__ Wf1,
        _Float16* __restrict__ Wf2) {
    if (blockIdx.x >= 392) {                 // fused wprep
        const int wsel = blockIdx.x - 392;
        const float* W = wsel ? W2 : W1;
        _Float16* Wf = wsel ? Wf2 : Wf1;
        const int M = wsel ? 64 : 128;
        const int NT = M / 16;
        for (int i = threadIdx.x; i < 8192; i += 256) {   // 16 frags x 512
            int f = i >> 9, r = i & 511;
            int lane = r >> 3, j = r & 7;
            int kc = f / NT, nt = f % NT;
            int k = kc * 32 + (lane >> 4) * 8 + j;
            int m = nt * 16 + (lane & 15);
            Wf[i] = (_Float16)W[k * M + m];
        }
        return;
    }
    __shared__ unsigned ent[4096];           // 16 KB
    __shared__ unsigned short ebkt[4096];    // 8 KB
    __shared__ unsigned hist[NBKT], gofs[NBKT];
    __shared__ int sflag;
    const int stride = detect_stride_block(raw1, &sflag);
    const int tid = threadIdx.x;
    for (int b = tid; b < NBKT; b += 256) hist[b] = 0u;
    __syncthreads();
    const long long e0 = (long long)blockIdx.x * 4096;
    #pragma unroll 4
    for (int it = 0; it < 16; it++) {
        long long e = e0 + it * 256 + tid;
        if (e < 2LL * N_EDGES) {
            int g2 = e >= N_EDGES;
            const int* raw = g2 ? raw2 : raw1;
            long long el = e - (g2 ? N_EDGES : 0);
            int s = raw[el * stride];
            int d = raw[((long long)N_EDGES + el) * stride];
            int gid = g2 * NPAD + d;
            int bkt = gid >> 8;
            int i = it * 256 + tid;
            ent[i] = ((unsigned)(gid & 255) << 16) | (unsigned)s;
            ebkt[i] = (unsigned short)bkt;
            atomicAdd(&hist[bkt], 1u);
        }
    }
    __syncthreads();
    for (int b = tid; b < NBKT; b += 256) {
        unsigned c = hist[b];
        gofs[b] = c ? atomicAdd(&bcount[b], c) : 0u;
    }
    __syncthreads();
    for (int b = tid; b < NBKT; b += 256) hist[b] = 0u;
    __syncthreads();
    #pragma unroll 4
    for (int it = 0; it < 16; it++) {
        long long e = e0 + it * 256 + tid;
        if (e < 2LL * N_EDGES) {
            int i = it * 256 + tid;
            int bkt = (int)ebkt[i];
            unsigned r = atomicAdd(&hist[bkt], 1u);
            unsigned pos = gofs[bkt] + r;
            if (pos < BCAP) bbuf[(size_t)bkt * BCAP + pos] = ent[i];
        }
    }
}

// ---------------------------------------------------------------------------
// Pass B: one block per bucket. Bucket-count scan -> CSR base; per-node
// degree + rowptr + dinv; LDS-cursor CSR scatter; fused fp16 prescale
// sxh = dinv * x for this bucket's 256 nodes.   [R7-verified]
// ---------------------------------------------------------------------------
__global__ __launch_bounds__(256) void buildB_k(const unsigned* __restrict__ bcount,
        const unsigned* __restrict__ bbuf, const float* __restrict__ x1,
        const float* __restrict__ x2, unsigned short* __restrict__ csr,
        int* __restrict__ rowptr, float* __restrict__ dinv,
        __half* __restrict__ sxh) {
    __shared__ unsigned ent[BCAP];
    __shared__ int deg[256], cur[256], tmp[256], tmp2[512];
    __shared__ float sdinv[256];
    const int b = blockIdx.x, tid = threadIdx.x;
    {
        int v = (tid < NBKT) ? (int)bcount[tid] : 0;
        tmp2[tid] = v; tmp2[tid + 256] = (tid + 256 < NBKT) ? (int)bcount[tid + 256] : 0;
        __syncthreads();
        #pragma unroll
        for (int off = 1; off < 512; off <<= 1) {
            int a0 = (tid >= off) ? tmp2[tid - off] : 0;
            int a1 = (tid + 256 >= off) ? tmp2[tid + 256 - off] : 0;
            __syncthreads();
            tmp2[tid] += a0; tmp2[tid + 256] += a1;
            __syncthreads();
        }
    }
    const int cnt = min((int)bcount[b], BCAP);
    const int eb = tmp2[b] - (int)bcount[b];
    for (int i = tid; i < cnt; i += 256) ent[i] = bbuf[(size_t)b * BCAP + i];
    deg[tid] = 0;
    __syncthreads();
    for (int i = tid; i < cnt; i += 256) atomicAdd(&deg[ent[i] >> 16], 1);
    __syncthreads();
    int v = deg[tid];
    tmp[tid] = v;
    __syncthreads();
    #pragma unroll
    for (int off = 1; off < 256; off <<= 1) {
        int add = (tid >= off) ? tmp[tid - off] : 0;
        __syncthreads();
        tmp[tid] += add;
        __syncthreads();
    }
    int excl = tmp[tid] - v;
    cur[tid] = excl;
    const int gid = b * 256 + tid;
    float dv = rsqrtf((float)v + 1.0f);          // +1 self-loop
    rowptr[gid] = eb + excl;
    dinv[gid] = dv;
    sdinv[tid] = dv;
    if (b == NBKT - 1 && tid == 255) rowptr[2 * NPAD] = eb + excl + v;
    __syncthreads();
    for (int i = tid; i < cnt; i += 256) {
        unsigned p = ent[i];
        int pos = atomicAdd(&cur[p >> 16], 1);
        csr[eb + pos] = (unsigned short)(p & 0xFFFFu);
    }
    const int g2 = (b * 256) >= NPAD;
    const float* x = g2 ? x2 : x1;
    const int lbase = b * 256 - (g2 ? NPAD : 0);
    for (int i = tid; i < 256 * 16; i += 256) {
        int n = i >> 4, q = i & 15;
        int local = lbase + n;
        __half2 lo = __floats2half2_rn(0.f, 0.f), hi = lo;
        if (local < N_NODES) {
            float4 vx = *(const float4*)&x[((size_t)local * 16 + q) * 4];
            float dn = sdinv[n];
            lo = __floats2half2_rn(vx.x * dn, vx.y * dn);
            hi = __floats2half2_rn(vx.z * dn, vx.w * dn);
        }
        uint2 u; u.x = *(unsigned*)&lo; u.y = *(unsigned*)&hi;
        *(uint2*)&sxh[(size_t)(b * 256 + n) * 64 + q * 4] = u;
    }
}

// ---------------------------------------------------------------------------
// Pull aggregation, LDS-staged indices + UNIFIED GUARDED 32-EDGE ROUNDS:
// block = 16 nodes; stage rowptr/dinv slices + csr window (<=LCAP u16) in
// LDS. Each wave: 4 nodes sequentially; per round, 8 independent guarded
// uint2 gathers per lane (past-end lanes clamp address to the row head and
// zero-mask the value -- fp16 zero-add is exact). Poisson(16) degrees =>
// ~1.0 latency rounds/node vs ~2.5 with a serial 4-edge remainder loop.
// ---------------------------------------------------------------------------
template<bool BIAS_RELU, bool COMPACT_OUT, bool OUT_HALF>
__global__ __launch_bounds__(256) void pull_agg_k(const __half* __restrict__ sh,
        const unsigned short* __restrict__ csr, const int* __restrict__ rowptr,
        const float* __restrict__ dinv, const float* __restrict__ bias,
        void* __restrict__ outv) {
    __shared__ unsigned short lcsr[LCAP];
    __shared__ int lrp[PBN + 1];
    __shared__ float ldv[PBN];
    const int tid = threadIdx.x;
    const int n0 = blockIdx.x * PBN;             // padded node base (no straddle)
    const int g2 = n0 >= NPAD;
    const int gbase = g2 ? NPAD : 0;
    if (tid <= PBN) lrp[tid] = rowptr[n0 + tid];
    if (tid < PBN)  ldv[tid] = dinv[n0 + tid];
    __syncthreads();
    const int wb = lrp[0];
    const int wcnt = min(lrp[PBN] - wb, LCAP);
    for (int i = tid; i < wcnt; i += 256) lcsr[i] = csr[wb + i];
    __syncthreads();
    const int wv = tid >> 6, lane = tid & 63;
    const int sub = lane >> 4, fl = lane & 15;
    float4 bv;
    if (BIAS_RELU) bv = *(const float4*)&bias[fl * 4];
    for (int r = 0; r < 4; r++) {
        const int n = wv * 4 + r;
        const int d = n0 + n;
        const int jfull = lrp[n + 1] - wb;
        const int jb = min(lrp[n] - wb, wcnt), je = min(jfull, wcnt);
        float4 acc = {0.f, 0.f, 0.f, 0.f};
        for (int j = jb; j < je; j += 32) {      // body runs only if jb < je
            uint2 u[8];
            int ok[8];
            #pragma unroll
            for (int k = 0; k < 8; k++) {
                int idx = j + k * 4 + sub;
                ok[k] = idx < je;
                int ii = ok[k] ? idx : jb;       // safe: row nonempty here
                int s = (int)lcsr[ii] + gbase;
                u[k] = *(const uint2*)&sh[(size_t)s * 64 + fl * 4];
            }
            #pragma unroll
            for (int k = 0; k < 8; k++)
                if (!ok[k]) { u[k].x = 0u; u[k].y = 0u; }
            #pragma unroll
            for (int k = 0; k < 8; k += 2) {
                __half2 pa = __hadd2(*(__half2*)&u[k].x, *(__half2*)&u[k + 1].x);
                __half2 pb = __hadd2(*(__half2*)&u[k].y, *(__half2*)&u[k + 1].y);
                float2 fa = __half22float2(pa), fb = __half22float2(pb);
                acc.x += fa.x; acc.y += fa.y; acc.z += fb.x; acc.w += fb.y;
            }
        }
        for (int j2 = je; j2 < jfull; j2 += 4) { // LCAP overflow: global, guarded
            int idx = j2 + sub;
            if (idx < jfull) {
                int s = (int)csr[wb + idx] + gbase;
                uint2 u = *(const uint2*)&sh[(size_t)s * 64 + fl * 4];
                float2 f0 = __half22float2(*(__half2*)&u.x);
                float2 f1 = __half22float2(*(__half2*)&u.y);
                acc.x += f0.x; acc.y += f0.y; acc.z += f1.x; acc.w += f1.y;
            }
        }
        acc.x += __shfl_xor(acc.x, 16); acc.y += __shfl_xor(acc.y, 16);
        acc.z += __shfl_xor(acc.z, 16); acc.w += __shfl_xor(acc.w, 16);
        acc.x += __shfl_xor(acc.x, 32); acc.y += __shfl_xor(acc.y, 32);
        acc.z += __shfl_xor(acc.z, 32); acc.w += __shfl_xor(acc.w, 32);
        uint2 su = *(const uint2*)&sh[(size_t)d * 64 + fl * 4];
        float2 sf0 = __half22float2(*(__half2*)&su.x);
        float2 sf1 = __half22float2(*(__half2*)&su.y);
        float dv = ldv[n];
        float4 o;
        o.x = (acc.x + sf0.x) * dv;
        o.y = (acc.y + sf0.y) * dv;
        o.z = (acc.z + sf1.x) * dv;
        o.w = (acc.w + sf1.y) * dv;
        if (BIAS_RELU) {
            o.x = fmaxf(o.x + bv.x, 0.f);
            o.y = fmaxf(o.y + bv.y, 0.f);
            o.z = fmaxf(o.z + bv.z, 0.f);
            o.w = fmaxf(o.w + bv.w, 0.f);
        }
        if (sub == 0) {
            if (OUT_HALF) {
                __half2 lo = __floats2half2_rn(o.x, o.y);
                __half2 hi = __floats2half2_rn(o.z, o.w);
                uint2 u; u.x = *(unsigned*)&lo; u.y = *(unsigned*)&hi;
                *(uint2*)&((__half*)outv)[(size_t)d * 64 + fl * 4] = u;  // padded
            } else {
                int local = d - gbase;
                if (!COMPACT_OUT) {
                    *(float4*)&((float*)outv)[(size_t)d * 64 + fl * 4] = o;
                } else if (local < N_NODES) {
                    size_t orow = (size_t)(g2 ? N_NODES + local : local);
                    *(float4*)&((float*)outv)[orow * 64 + fl * 4] = o;
                }
            }
        }
    }
}

// ---------------------------------------------------------------------------
// FUSED double MFMA GEMM [R11-verified]: GH = dinv * (relu(Y@W1 + b1) @ W2),
// per 128-row block, X1 routed through LDS (stride X1S=136 halfs).
// C/D layout col=lane&15, row=(lane>>4)*4+reg. Grid 784 exact.
// ---------------------------------------------------------------------------
__global__ __launch_bounds__(256) void gemm12_k(const _Float16* __restrict__ Y,
        const _Float16* __restrict__ Wf1, const float* __restrict__ b1,
        const _Float16* __restrict__ Wf2, const float* __restrict__ dinv,
        _Float16* __restrict__ GH) {
    __shared__ _Float16 X1l[128 * X1S];      // 34.8 KB
    const int tid = threadIdx.x;
    const int wv = tid >> 6, lane = tid & 63;
    const int quad = lane >> 4, c = lane & 15;
    const int lrow0 = wv * 32;               // wave's 32 local rows
    const int grow0 = blockIdx.x * 128 + lrow0;
    // ---- phase 1: X1 = relu(Y @ W1 + b1) -> LDS ----
    {
        half8 bf[2][8];                      // K=64 (KC=2), M=128 (NT=8)
        #pragma unroll
        for (int kc = 0; kc < 2; kc++)
            #pragma unroll
            for (int nt = 0; nt < 8; nt++)
                bf[kc][nt] = *(const half8*)&Wf1[((kc * 8 + nt) * 64 + lane) * 8];
        floatx4 acc[2][8] = {};
        #pragma unroll
        for (int rt = 0; rt < 2; rt++) {
            half8 a[2];
            #pragma unroll
            for (int kc = 0; kc < 2; kc++)
                a[kc] = *(const half8*)&Y[(size_t)(grow0 + rt * 16 + c) * 64 + kc * 32 + quad * 8];
            #pragma unroll
            for (int nt = 0; nt < 8; nt++)
                #pragma unroll
                for (int kc = 0; kc < 2; kc++)
                    acc[rt][nt] = __builtin_amdgcn_mfma_f32_16x16x32_f16(
                        a[kc], bf[kc][nt], acc[rt][nt], 0, 0, 0);
        }
        float bv[8];
        #pragma unroll
        for (int nt = 0; nt < 8; nt++) bv[nt] = b1[nt * 16 + c];
        #pragma unroll
        for (int rt = 0; rt < 2; rt++)
            #pragma unroll
            for (int nt = 0; nt < 8; nt++)
                #pragma unroll
                for (int reg = 0; reg < 4; reg++) {
                    float v = fmaxf(acc[rt][nt][reg] + bv[nt], 0.f);
                    X1l[(lrow0 + rt * 16 + quad * 4 + reg) * X1S + nt * 16 + c] = (_Float16)v;
                }
    }
    __syncthreads();
    // ---- phase 2: GH = dinv * (X1 @ W2) ----
    {
        half8 bf[4][4];                      // K=128 (KC=4), M=64 (NT=4)
        #pragma unroll
        for (int kc = 0; kc < 4; kc++)
            #pragma unroll
            for (int nt = 0; nt < 4; nt++)
                bf[kc][nt] = *(const half8*)&Wf2[((kc * 4 + nt) * 64 + lane) * 8];
        floatx4 acc[2][4] = {};
        #pragma unroll
        for (int rt = 0; rt < 2; rt++) {
            half8 a[4];
            #pragma unroll
            for (int kc = 0; kc < 4; kc++)
                a[kc] = *(const half8*)&X1l[(lrow0 + rt * 16 + c) * X1S + kc * 32 + quad * 8];
            #pragma unroll
            for (int nt = 0; nt < 4; nt++)
                #pragma unroll
                for (int kc = 0; kc < 4; kc++)
                    acc[rt][nt] = __builtin_amdgcn_mfma_f32_16x16x32_f16(
                        a[kc], bf[kc][nt], acc[rt][nt], 0, 0, 0);
        }
        #pragma unroll
        for (int rt = 0; rt < 2; rt++) {
            const int rbase = grow0 + rt * 16 + quad * 4;
            float4 dvv = *(const float4*)&dinv[rbase];
            #pragma unroll
            for (int nt = 0; nt < 4; nt++)
                #pragma unroll
                for (int reg = 0; reg < 4; reg++) {
                    float v = acc[rt][nt][reg] * ((const float*)&dvv)[reg];
                    GH[(size_t)(rbase + reg) * 64 + nt * 16 + c] = (_Float16)v;
                }
        }
    }
}

extern "C" void kernel_launch(void* const* d_in, const int* in_sizes, int n_in,
                              void* d_out, int out_size, void* d_ws, size_t ws_size,
                              hipStream_t stream) {
    const float* x1 = (const float*)d_in[0];
    const int*   e1 = (const int*)d_in[1];
    const float* x2 = (const float*)d_in[2];
    const int*   e2 = (const int*)d_in[3];
    const float* W1 = (const float*)d_in[4];
    const float* b1 = (const float*)d_in[5];
    const float* W2 = (const float*)d_in[6];
    const float* b2 = (const float*)d_in[7];
    float* out = (float*)d_out;

    // Workspace (~45 MB), 256 B-aligned chunks.
    char* p = (char*)d_ws;
    auto alloc = [&](size_t bytes) { char* r = p; p += (bytes + 255) & ~(size_t)255; return r; };
    unsigned* bcount = (unsigned*)alloc(NBKT * 4);
    float*    dinv   = (float*)alloc((size_t)2 * NPAD * 4);
    int*      rowptr = (int*)alloc(((size_t)2 * NPAD + 1) * 4);
    unsigned* bbuf   = (unsigned*)alloc((size_t)NBKT * BCAP * 4);
    unsigned short* csr = (unsigned short*)alloc((size_t)2 * N_EDGES * 2);
    __half*   sxh    = (__half*)alloc((size_t)2 * NPAD * 64 * 2);    // fp16 feats
    _Float16* bufYh  = (_Float16*)alloc((size_t)2 * NPAD * 64 * 2);  // fp16 Y
    _Float16* Wf1    = (_Float16*)alloc(8192 * 2);
    _Float16* Wf2    = (_Float16*)alloc(8192 * 2);
    __half*   gh     = sxh;   // alias: sxh dead after pull-1; gemm12 writes gh

    // ---- CSR build + dinv + fp16 prescale + W fragment pack (fused) ----
    hipMemsetAsync(bcount, 0, NBKT * 4, stream);
    binA_k<<<394, 256, 0, stream>>>(e1, e2, W1, W2, bcount, bbuf, Wf1, Wf2);
    buildB_k<<<NBKT, 256, 0, stream>>>(bcount, bbuf, x1, x2, csr, rowptr, dinv, sxh);

    // ---- layer 1 agg: Y = A_hat @ X (fp16) ----
    pull_agg_k<false, false, true><<<2 * NPAD / PBN, 256, 0, stream>>>(
        sxh, csr, rowptr, dinv, nullptr, bufYh);
    // ---- fused GEMMs: G' = fp16(dinv * (relu(Y@W1+b1) @ W2)) ----
    gemm12_k<<<784, 256, 0, stream>>>(bufYh, Wf1, b1, Wf2, dinv, (_Float16*)gh);
    // ---- layer 2 agg + epilogue: out = relu(dinv*(sum+self)+b2) ----
    pull_agg_k<true, true, false><<<2 * NPAD / PBN, 256, 0, stream>>>(
        gh, csr, rowptr, dinv, b2, out);
}